// Round 2
// baseline (11156.789 us; speedup 1.0000x reference)
//
#include <hip/hip_runtime.h>

typedef __attribute__((ext_vector_type(8))) short bf16x8;
typedef __attribute__((ext_vector_type(4))) float f32x4;

#define DEV __device__ __forceinline__

DEV ushort f2b(float f) {
  unsigned u = __float_as_uint(f);
  u += 0x7fffu + ((u >> 16) & 1u);   // RNE to bf16
  return (ushort)(u >> 16);
}
DEV float b2f(ushort u) { return __uint_as_float(((unsigned)u) << 16); }

// ---------------- zero scalar slots ----------------
__global__ void k_zero(unsigned* p, int n) {
  int i = blockIdx.x * blockDim.x + threadIdx.x;
  if (i < n) p[i] = 0u;
}

// ------------- weight transpose fp32 W[K][N] -> bf16 WT[N][K] -------------
__global__ __launch_bounds__(256) void k_wt(const float* __restrict__ W,
                                            ushort* __restrict__ WT, int K, int N) {
  __shared__ float T[32][33];
  int k0 = blockIdx.y * 32, n0 = blockIdx.x * 32;
  int tx = threadIdx.x & 31, ty = threadIdx.x >> 5;
  for (int r = ty; r < 32; r += 8) {
    int k = k0 + r, n = n0 + tx;
    T[r][tx] = (k < K && n < N) ? W[(size_t)k * N + n] : 0.f;
  }
  __syncthreads();
  for (int r = ty; r < 32; r += 8) {
    int n = n0 + r, k = k0 + tx;
    if (n < N && k < K) WT[(size_t)n * K + k] = f2b(T[tx][r]);
  }
}

// ---------------- f32 -> bf16 elementwise ----------------
__global__ void k_cvt(const float* __restrict__ in, ushort* __restrict__ out, int n) {
  int i = blockIdx.x * 256 + threadIdx.x;
  if (i < n) out[i] = f2b(in[i]);
}

// ---------------- layernorm (C==1280), out bf16 ----------------
__global__ __launch_bounds__(256) void k_ln(const float* __restrict__ x,
    const float* __restrict__ g, const float* __restrict__ b,
    ushort* __restrict__ out) {
  const int C = 1280;
  int row = blockIdx.x, tid = threadIdx.x;
  const float* xr = x + (size_t)row * C;
  float v[5];
  float s = 0.f, ss = 0.f;
  for (int i = 0; i < 5; i++) {
    v[i] = xr[tid + i * 256];
    s += v[i]; ss += v[i] * v[i];
  }
  for (int off = 32; off; off >>= 1) {
    s += __shfl_down(s, off);
    ss += __shfl_down(ss, off);
  }
  __shared__ float red[8];
  __shared__ float mu_s, rstd_s;
  int wave = tid >> 6, lane = tid & 63;
  if (lane == 0) { red[wave] = s; red[4 + wave] = ss; }
  __syncthreads();
  if (tid == 0) {
    float S = red[0] + red[1] + red[2] + red[3];
    float SS = red[4] + red[5] + red[6] + red[7];
    float mu = S / C;
    float var = SS / C - mu * mu;
    mu_s = mu;
    rstd_s = rsqrtf(var + 1e-5f);
  }
  __syncthreads();
  float mu = mu_s, rstd = rstd_s;
  for (int i = 0; i < 5; i++) {
    int c = tid + i * 256;
    out[(size_t)row * C + c] = f2b((v[i] - mu) * rstd * g[c] + b[c]);
  }
}

// ---------------- bf16 NT GEMM: C[M,N] = A[M,K] @ BT[N,K]^T ----------------
// 128x128 tile, 4 waves (2x2 of 64x64), 16x16x32 MFMA, BK=32.
__global__ __launch_bounds__(256, 2) void k_gemm(
    const ushort* __restrict__ A, int lda,
    const ushort* __restrict__ BT, int ldb,
    float* __restrict__ Cf, ushort* __restrict__ Cb, int ldc,
    const float* __restrict__ bias, const float* __restrict__ resid,
    unsigned* am_slot, int M, int N, int K) {
  __shared__ __align__(16) ushort As[128][40];
  __shared__ __align__(16) ushort Bs[128][40];
  int tid = threadIdx.x;
  int wave = tid >> 6, lane = tid & 63;
  int q = lane >> 4, mi = lane & 15;
  int wr = (wave >> 1) * 64, wc = (wave & 1) * 64;
  int bm0 = blockIdx.y * 128, bn0 = blockIdx.x * 128;
  f32x4 acc[4][4] = {};
  for (int k0 = 0; k0 < K; k0 += 32) {
    __syncthreads();
    for (int c = tid; c < 512; c += 256) {
      int r = c >> 2, kc = (c & 3) << 3;
      int gr = bm0 + r; gr = gr < M ? gr : M - 1;
      *(int4*)&As[r][kc] = *(const int4*)(A + (size_t)gr * lda + k0 + kc);
      int gn = bn0 + r; gn = gn < N ? gn : N - 1;
      *(int4*)&Bs[r][kc] = *(const int4*)(BT + (size_t)gn * ldb + k0 + kc);
    }
    __syncthreads();
    bf16x8 af[4], bf[4];
    for (int i = 0; i < 4; i++) {
      af[i] = *(const bf16x8*)&As[wr + i * 16 + mi][q * 8];
      bf[i] = *(const bf16x8*)&Bs[wc + i * 16 + mi][q * 8];
    }
    for (int i = 0; i < 4; i++)
      for (int j = 0; j < 4; j++)
        acc[i][j] = __builtin_amdgcn_mfma_f32_16x16x32_bf16(af[i], bf[j], acc[i][j], 0, 0, 0);
  }
  float am = 0.f;
  for (int i = 0; i < 4; i++)
    for (int j = 0; j < 4; j++)
      for (int reg = 0; reg < 4; reg++) {
        int r_ = bm0 + wr + i * 16 + q * 4 + reg;
        int c_ = bn0 + wc + j * 16 + mi;
        float v = acc[i][j][reg];
        am = fmaxf(am, fabsf(v));
        if (r_ < M && c_ < N) {
          if (bias) v += bias[c_];
          if (resid) v += resid[(size_t)r_ * ldc + c_];
          if (Cf) Cf[(size_t)r_ * ldc + c_] = v;
          if (Cb) Cb[(size_t)r_ * ldc + c_] = f2b(v);
        }
      }
  if (am_slot) {
    for (int off = 32; off; off >>= 1) am = fmaxf(am, __shfl_down(am, off));
    if (lane == 0) atomicMax(am_slot, __float_as_uint(am));
  }
}

// ---------------- symmetric fake-quant, in-place on bf16 ----------------
__global__ void k_quant(const ushort* __restrict__ in, ushort* __restrict__ out,
                        const unsigned* __restrict__ slot, int n) {
  int i = blockIdx.x * 256 + threadIdx.x;
  if (i >= n) return;
  float delta = fmaxf(__uint_as_float(*slot), 1e-8f) * (1.f / 127.f);
  float x = b2f(in[i]);
  float y = fminf(fmaxf(rintf(x / delta), -128.f), 127.f) * delta;
  out[i] = f2b(y);
}

// ------- V transpose per head: vq[b*Mr+m][h*64+d] -> vT[bh][d][m] (zero-pad) -------
__global__ __launch_bounds__(256) void k_vt(const ushort* __restrict__ vq,
    ushort* __restrict__ vT, int H, int Mr, int Mpad) {
  const int C = 1280;
  __shared__ __align__(16) ushort T[64][72];
  int bh = blockIdx.y, b = bh / H, h = bh % H;
  int m0 = blockIdx.x * 64;
  int tid = threadIdx.x;
  for (int c = tid; c < 512; c += 256) {
    int mm = c >> 3, dc = (c & 7) << 3;
    int m = m0 + mm;
    int4 val = make_int4(0, 0, 0, 0);
    if (m < Mr) val = *(const int4*)(vq + ((size_t)b * Mr + m) * C + h * 64 + dc);
    *(int4*)&T[mm][dc] = val;
  }
  __syncthreads();
  for (int c = tid; c < 512; c += 256) {
    int dd = c >> 3, mc = (c & 7) << 3;
    unsigned w0 = (unsigned)T[mc + 0][dd] | ((unsigned)T[mc + 1][dd] << 16);
    unsigned w1 = (unsigned)T[mc + 2][dd] | ((unsigned)T[mc + 3][dd] << 16);
    unsigned w2 = (unsigned)T[mc + 4][dd] | ((unsigned)T[mc + 5][dd] << 16);
    unsigned w3 = (unsigned)T[mc + 6][dd] | ((unsigned)T[mc + 7][dd] << 16);
    int4 val = make_int4((int)w0, (int)w1, (int)w2, (int)w3);
    *(int4*)(vT + ((size_t)bh * 64 + dd) * Mpad + m0 + mc) = val;
  }
}

// ------- attention phase 1: per-row smax & Z, global max(1/Z) -> pmax -------
__global__ __launch_bounds__(256) void k_attn1(
    const ushort* __restrict__ qq, const ushort* __restrict__ kq,
    float2* __restrict__ rs, unsigned* __restrict__ pmax,
    int H, int N, int Mr, float scale) {
  const int C = 1280;
  __shared__ __align__(16) ushort Qs[64][72];
  __shared__ __align__(16) ushort Ks[64][72];
  __shared__ float Ss[64][68];
  __shared__ float mq4[64][4], zq4[64][4];
  int tid = threadIdx.x;
  int wave = tid >> 6, lane = tid & 63;
  int q = lane >> 4, mi = lane & 15;
  int bh = blockIdx.y, b = bh / H, h = bh % H;
  int r0 = blockIdx.x * 64;
  for (int c = tid; c < 512; c += 256) {
    int r = c >> 3, dc = (c & 7) << 3;
    *(int4*)&Qs[r][dc] = *(const int4*)(qq + ((size_t)b * N + r0 + r) * C + h * 64 + dc);
  }
  float m_run = -1e30f, z_run = 0.f;
  int row = tid >> 2, qt = tid & 3;
  int nt = (Mr + 63) >> 6;
  for (int mt = 0; mt < nt; mt++) {
    __syncthreads();
    for (int c = tid; c < 512; c += 256) {
      int mm = c >> 3, dc = (c & 7) << 3;
      int m = mt * 64 + mm;
      int4 val = make_int4(0, 0, 0, 0);
      if (m < Mr) val = *(const int4*)(kq + ((size_t)b * Mr + m) * C + h * 64 + dc);
      *(int4*)&Ks[mm][dc] = val;
    }
    __syncthreads();
    f32x4 sacc[4] = {};
    for (int kc = 0; kc < 2; kc++) {
      bf16x8 aq = *(const bf16x8*)&Qs[wave * 16 + mi][kc * 32 + q * 8];
      for (int j = 0; j < 4; j++) {
        bf16x8 bk = *(const bf16x8*)&Ks[j * 16 + mi][kc * 32 + q * 8];
        sacc[j] = __builtin_amdgcn_mfma_f32_16x16x32_bf16(aq, bk, sacc[j], 0, 0, 0);
      }
    }
    for (int j = 0; j < 4; j++)
      for (int reg = 0; reg < 4; reg++)
        Ss[wave * 16 + q * 4 + reg][j * 16 + mi] = sacc[j][reg] * scale;
    __syncthreads();
    for (int cc = 0; cc < 16; cc++) {
      int col = qt * 16 + cc;
      int mg = mt * 64 + col;
      if (mg < Mr) {
        float sv = Ss[row][col];
        if (sv <= m_run) {
          z_run += __expf(sv - m_run);
        } else {
          z_run = z_run * __expf(m_run - sv) + 1.f;
          m_run = sv;
        }
      }
    }
  }
  __syncthreads();
  mq4[row][qt] = m_run; zq4[row][qt] = z_run;
  __syncthreads();
  if (tid < 64) {
    float M_ = mq4[tid][0];
    for (int k = 1; k < 4; k++) M_ = fmaxf(M_, mq4[tid][k]);
    float Z = 0.f;
    for (int k = 0; k < 4; k++) Z += zq4[tid][k] * __expf(mq4[tid][k] - M_);
    float2 st; st.x = M_; st.y = Z;
    rs[(size_t)bh * N + r0 + tid] = st;
    float pm = 1.f / Z;
    for (int off = 32; off; off >>= 1) pm = fmaxf(pm, __shfl_down(pm, off));
    if (tid == 0) atomicMax(pmax, __float_as_uint(pm));
  }
}

// ------- attention phase 2: recompute S, quantize probs, P@V -> ao (bf16) -------
__global__ __launch_bounds__(256) void k_attn2(
    const ushort* __restrict__ qq, const ushort* __restrict__ kq,
    const ushort* __restrict__ vT, const float2* __restrict__ rs,
    const unsigned* __restrict__ pmax, ushort* __restrict__ ao,
    int H, int N, int Mr, int Mpad, float scale) {
  const int C = 1280;
  __shared__ __align__(16) ushort Qs[64][72];
  __shared__ __align__(16) ushort Ks[64][72];
  __shared__ __align__(16) ushort Vs[64][72];
  __shared__ __align__(16) ushort Ps[64][72];
  __shared__ float Ss[64][68];
  int tid = threadIdx.x;
  int wave = tid >> 6, lane = tid & 63;
  int q = lane >> 4, mi = lane & 15;
  int bh = blockIdx.y, b = bh / H, h = bh % H;
  int r0 = blockIdx.x * 64;
  for (int c = tid; c < 512; c += 256) {
    int r = c >> 3, dc = (c & 7) << 3;
    *(int4*)&Qs[r][dc] = *(const int4*)(qq + ((size_t)b * N + r0 + r) * C + h * 64 + dc);
  }
  int row = tid >> 2, qt = tid & 3;
  float2 st = rs[(size_t)bh * N + r0 + row];
  float delta = fmaxf(__uint_as_float(*pmax), 1e-8f) * (1.f / 255.f);
  float invd = 1.f / delta;
  f32x4 oacc[4] = {};
  int nt = (Mr + 63) >> 6;
  for (int mt = 0; mt < nt; mt++) {
    __syncthreads();
    for (int c = tid; c < 512; c += 256) {
      int mm = c >> 3, dc = (c & 7) << 3;
      int m = mt * 64 + mm;
      int4 val = make_int4(0, 0, 0, 0);
      if (m < Mr) val = *(const int4*)(kq + ((size_t)b * Mr + m) * C + h * 64 + dc);
      *(int4*)&Ks[mm][dc] = val;
      *(int4*)&Vs[mm][dc] = *(const int4*)(vT + ((size_t)bh * 64 + mm) * Mpad + mt * 64 + dc);
    }
    __syncthreads();
    f32x4 sacc[4] = {};
    for (int kc = 0; kc < 2; kc++) {
      bf16x8 aq = *(const bf16x8*)&Qs[wave * 16 + mi][kc * 32 + q * 8];
      for (int j = 0; j < 4; j++) {
        bf16x8 bk = *(const bf16x8*)&Ks[j * 16 + mi][kc * 32 + q * 8];
        sacc[j] = __builtin_amdgcn_mfma_f32_16x16x32_bf16(aq, bk, sacc[j], 0, 0, 0);
      }
    }
    for (int j = 0; j < 4; j++)
      for (int reg = 0; reg < 4; reg++)
        Ss[wave * 16 + q * 4 + reg][j * 16 + mi] = sacc[j][reg] * scale;
    __syncthreads();
    for (int cc = 0; cc < 16; cc++) {
      int col = qt * 16 + cc;
      int mg = mt * 64 + col;
      float p = 0.f;
      if (mg < Mr) {
        float sv = Ss[row][col];
        p = __expf(sv - st.x) / st.y;
        p = fminf(rintf(p * invd), 255.f) * delta;
      }
      Ps[row][col] = f2b(p);
    }
    __syncthreads();
    for (int kc = 0; kc < 2; kc++) {
      bf16x8 ap = *(const bf16x8*)&Ps[wave * 16 + mi][kc * 32 + q * 8];
      for (int j = 0; j < 4; j++) {
        bf16x8 bv = *(const bf16x8*)&Vs[j * 16 + mi][kc * 32 + q * 8];
        oacc[j] = __builtin_amdgcn_mfma_f32_16x16x32_bf16(ap, bv, oacc[j], 0, 0, 0);
      }
    }
  }
  for (int j = 0; j < 4; j++)
    for (int reg = 0; reg < 4; reg++) {
      int r_ = r0 + wave * 16 + q * 4 + reg;
      int d_ = j * 16 + mi;
      ao[((size_t)b * N + r_) * C + h * 64 + d_] = f2b(oacc[j][reg]);
    }
}

// ------- fused FF1 + GEGLU: GG[r][c] = (A@W)[r][c]+b  *  gelu((A@W)[r][c+5120]+b) -------
__global__ __launch_bounds__(256, 2) void k_ff1(
    const ushort* __restrict__ A,          // LN [8192][1280]
    const ushort* __restrict__ BT,         // WF1T [10240][1280]
    const float* __restrict__ bias,        // bff1 [10240]
    ushort* __restrict__ GG) {             // [8192][5120]
  const int K = 1280;
  __shared__ __align__(16) ushort As[128][40];
  __shared__ __align__(16) ushort Ba[128][40];
  __shared__ __align__(16) ushort Bg[128][40];
  int tid = threadIdx.x;
  int wave = tid >> 6, lane = tid & 63;
  int q = lane >> 4, mi = lane & 15;
  int wr = (wave >> 1) * 64, wc = (wave & 1) * 64;
  int bm0 = blockIdx.y * 128, bn0 = blockIdx.x * 128;
  f32x4 acca[4][4] = {}, accg[4][4] = {};
  for (int k0 = 0; k0 < K; k0 += 32) {
    __syncthreads();
    for (int c = tid; c < 512; c += 256) {
      int r = c >> 2, kc = (c & 3) << 3;
      *(int4*)&As[r][kc] = *(const int4*)(A + (size_t)(bm0 + r) * K + k0 + kc);
      *(int4*)&Ba[r][kc] = *(const int4*)(BT + (size_t)(bn0 + r) * K + k0 + kc);
      *(int4*)&Bg[r][kc] = *(const int4*)(BT + (size_t)(5120 + bn0 + r) * K + k0 + kc);
    }
    __syncthreads();
    bf16x8 af[4], ba[4], bg[4];
    for (int i = 0; i < 4; i++) {
      af[i] = *(const bf16x8*)&As[wr + i * 16 + mi][q * 8];
      ba[i] = *(const bf16x8*)&Ba[wc + i * 16 + mi][q * 8];
      bg[i] = *(const bf16x8*)&Bg[wc + i * 16 + mi][q * 8];
    }
    for (int i = 0; i < 4; i++)
      for (int j = 0; j < 4; j++) {
        acca[i][j] = __builtin_amdgcn_mfma_f32_16x16x32_bf16(af[i], ba[j], acca[i][j], 0, 0, 0);
        accg[i][j] = __builtin_amdgcn_mfma_f32_16x16x32_bf16(af[i], bg[j], accg[i][j], 0, 0, 0);
      }
  }
  for (int i = 0; i < 4; i++)
    for (int j = 0; j < 4; j++)
      for (int reg = 0; reg < 4; reg++) {
        int r_ = bm0 + wr + i * 16 + q * 4 + reg;
        int c_ = bn0 + wc + j * 16 + mi;
        float a = acca[i][j][reg] + bias[c_];
        float g = accg[i][j][reg] + bias[5120 + c_];
        float y = 0.7978845608028654f * (g + 0.044715f * g * g * g);
        float gel = 0.5f * g * (1.f + tanhf(y));
        GG[(size_t)r_ * 5120 + c_] = f2b(a * gel);
      }
}

extern "C" void kernel_launch(void* const* d_in, const int* in_sizes, int n_in,
                              void* d_out, int out_size, void* d_ws, size_t ws_size,
                              hipStream_t stream) {
  const float* x_in = (const float*)d_in[0];
  const float* ctx  = (const float*)d_in[1];
  const float* ln1g = (const float*)d_in[2];
  const float* ln1b = (const float*)d_in[3];
  const float* ln2g = (const float*)d_in[4];
  const float* ln2b = (const float*)d_in[5];
  const float* ln3g = (const float*)d_in[6];
  const float* ln3b = (const float*)d_in[7];
  const float* Wq1  = (const float*)d_in[8];
  const float* Wk1  = (const float*)d_in[9];
  const float* Wv1  = (const float*)d_in[10];
  const float* Wo1  = (const float*)d_in[11];
  const float* bo1  = (const float*)d_in[12];
  const float* Wq2  = (const float*)d_in[13];
  const float* Wk2  = (const float*)d_in[14];
  const float* Wv2  = (const float*)d_in[15];
  const float* Wo2  = (const float*)d_in[16];
  const float* bo2  = (const float*)d_in[17];
  const float* Wff1 = (const float*)d_in[18];
  const float* bff1 = (const float*)d_in[19];
  const float* Wff2 = (const float*)d_in[20];
  const float* bff2 = (const float*)d_in[21];
  float* out = (float*)d_out;   // also doubles as the fp32 residual stream "xcur"

  const int NR = 8192;   // B*N
  const int C = 1280, H = 20, Nseq = 1024, CC = 768;
  const int MR2 = 616;   // B*M (cross rows)

  char* ws = (char*)d_ws;
  size_t off = 0;
  auto alloc = [&](size_t bytes) -> void* {
    void* p = ws + off;
    off += (bytes + 255) & ~(size_t)255;
    return p;
  };
  unsigned* scal = (unsigned*)alloc(64);
  ushort* Wq1T  = (ushort*)alloc((size_t)C * C * 2);
  ushort* Wk1T  = (ushort*)alloc((size_t)C * C * 2);
  ushort* Wv1T  = (ushort*)alloc((size_t)C * C * 2);
  ushort* Wo1T  = (ushort*)alloc((size_t)C * C * 2);
  ushort* Wq2T  = (ushort*)alloc((size_t)C * C * 2);
  ushort* Wk2T  = (ushort*)alloc((size_t)C * CC * 2);
  ushort* Wv2T  = (ushort*)alloc((size_t)C * CC * 2);
  ushort* Wo2T  = (ushort*)alloc((size_t)C * C * 2);
  ushort* WF1T  = (ushort*)alloc((size_t)10240 * C * 2);
  ushort* WF2T  = (ushort*)alloc((size_t)C * 5120 * 2);
  ushort* LN    = (ushort*)alloc((size_t)NR * C * 2);
  size_t regionR = off;  // attention region; stage-3 GG overlays it
  ushort* QQ    = (ushort*)alloc((size_t)NR * C * 2);
  ushort* KQ    = (ushort*)alloc((size_t)NR * C * 2);
  ushort* VQ    = (ushort*)alloc((size_t)NR * C * 2);  // also AO after k_vt
  ushort* VT    = (ushort*)alloc((size_t)160 * 64 * 1024 * 2);
  float2* RS    = (float2*)alloc((size_t)160 * 1024 * 8);
  ushort* CTXB  = (ushort*)alloc((size_t)MR2 * CC * 2);
  size_t need = off;
  ushort* AO = VQ;                       // alias: VQ dead once VT is built
  ushort* GG = (ushort*)(ws + regionR);  // 84 MB, overlays QQ..VT in stage 3
  if (ws_size < need) return;  // diagnostic: absmax==poison => ws too small

  // --- init & weight prep ---
  k_zero<<<1, 64, 0, stream>>>(scal, 8);
  k_wt<<<dim3(40, 40), 256, 0, stream>>>(Wq1, Wq1T, C, C);
  k_wt<<<dim3(40, 40), 256, 0, stream>>>(Wk1, Wk1T, C, C);
  k_wt<<<dim3(40, 40), 256, 0, stream>>>(Wv1, Wv1T, C, C);
  k_wt<<<dim3(40, 40), 256, 0, stream>>>(Wo1, Wo1T, C, C);
  k_wt<<<dim3(40, 40), 256, 0, stream>>>(Wq2, Wq2T, C, C);
  k_wt<<<dim3(40, 24), 256, 0, stream>>>(Wk2, Wk2T, CC, C);
  k_wt<<<dim3(40, 24), 256, 0, stream>>>(Wv2, Wv2T, CC, C);
  k_wt<<<dim3(40, 40), 256, 0, stream>>>(Wo2, Wo2T, C, C);
  k_wt<<<dim3(320, 40), 256, 0, stream>>>(Wff1, WF1T, C, 10240);
  k_wt<<<dim3(40, 160), 256, 0, stream>>>(Wff2, WF2T, 5120, C);

  // ================= stage 1: self-attention =================
  k_ln<<<NR, 256, 0, stream>>>(x_in, ln1g, ln1b, LN);
  k_gemm<<<dim3(10, 64), 256, 0, stream>>>(LN, C, Wq1T, C, nullptr, QQ, C,
                                           nullptr, nullptr, scal + 0, NR, C, C);
  k_quant<<<(NR * C + 255) / 256, 256, 0, stream>>>(QQ, QQ, scal + 0, NR * C);
  k_gemm<<<dim3(10, 64), 256, 0, stream>>>(LN, C, Wk1T, C, nullptr, KQ, C,
                                           nullptr, nullptr, scal + 1, NR, C, C);
  k_quant<<<(NR * C + 255) / 256, 256, 0, stream>>>(KQ, KQ, scal + 1, NR * C);
  k_gemm<<<dim3(10, 64), 256, 0, stream>>>(LN, C, Wv1T, C, nullptr, VQ, C,
                                           nullptr, nullptr, scal + 2, NR, C, C);
  k_quant<<<(NR * C + 255) / 256, 256, 0, stream>>>(VQ, VQ, scal + 2, NR * C);
  k_vt<<<dim3(16, 160), 256, 0, stream>>>(VQ, VT, H, 1024, 1024);
  k_attn1<<<dim3(16, 160), 256, 0, stream>>>(QQ, KQ, RS, scal + 3, H, Nseq, 1024, 0.125f);
  k_attn2<<<dim3(16, 160), 256, 0, stream>>>(QQ, KQ, VT, RS, scal + 3, AO,
                                             H, Nseq, 1024, 1024, 0.125f);
  k_gemm<<<dim3(10, 64), 256, 0, stream>>>(AO, C, Wo1T, C, out, nullptr, C,
                                           bo1, x_in, nullptr, NR, C, C);

  // ================= stage 2: cross-attention =================
  k_ln<<<NR, 256, 0, stream>>>(out, ln2g, ln2b, LN);
  k_gemm<<<dim3(10, 64), 256, 0, stream>>>(LN, C, Wq2T, C, nullptr, QQ, C,
                                           nullptr, nullptr, scal + 4, NR, C, C);
  k_quant<<<(NR * C + 255) / 256, 256, 0, stream>>>(QQ, QQ, scal + 4, NR * C);
  k_cvt<<<(MR2 * CC + 255) / 256, 256, 0, stream>>>(ctx, CTXB, MR2 * CC);
  k_gemm<<<dim3(10, 5), 256, 0, stream>>>(CTXB, CC, Wk2T, CC, nullptr, KQ, C,
                                          nullptr, nullptr, scal + 5, MR2, C, CC);
  k_quant<<<(MR2 * C + 255) / 256, 256, 0, stream>>>(KQ, KQ, scal + 5, MR2 * C);
  k_gemm<<<dim3(10, 5), 256, 0, stream>>>(CTXB, CC, Wv2T, CC, nullptr, VQ, C,
                                          nullptr, nullptr, scal + 6, MR2, C, CC);
  k_quant<<<(MR2 * C + 255) / 256, 256, 0, stream>>>(VQ, VQ, scal + 6, MR2 * C);
  k_vt<<<dim3(2, 160), 256, 0, stream>>>(VQ, VT, H, 77, 128);
  k_attn1<<<dim3(16, 160), 256, 0, stream>>>(QQ, KQ, RS, scal + 7, H, Nseq, 77, 0.125f);
  k_attn2<<<dim3(16, 160), 256, 0, stream>>>(QQ, KQ, VT, RS, scal + 7, AO,
                                             H, Nseq, 77, 128, 0.125f);
  k_gemm<<<dim3(10, 64), 256, 0, stream>>>(AO, C, Wo2T, C, out, nullptr, C,
                                           bo2, out, nullptr, NR, C, C);

  // ================= stage 3: GEGLU FF (fused, no H1 materialization) =================
  k_ln<<<NR, 256, 0, stream>>>(out, ln3g, ln3b, LN);
  k_ff1<<<dim3(40, 64), 256, 0, stream>>>(LN, WF1T, bff1, GG);
  k_gemm<<<dim3(10, 64), 256, 0, stream>>>(GG, 5120, WF2T, 5120, out, nullptr, C,
                                           bff2, out, nullptr, NR, C, 5120);
}

// Round 3
// 7320.411 us; speedup vs baseline: 1.5241x; 1.5241x over previous
//
#include <hip/hip_runtime.h>

typedef __attribute__((ext_vector_type(8))) short bf16x8;
typedef __attribute__((ext_vector_type(4))) float f32x4;

#define DEV __device__ __forceinline__

DEV ushort f2b(float f) {
  unsigned u = __float_as_uint(f);
  u += 0x7fffu + ((u >> 16) & 1u);   // RNE to bf16
  return (ushort)(u >> 16);
}
DEV float b2f(ushort u) { return __uint_as_float(((unsigned)u) << 16); }

// async global->LDS, 16B per lane; lds base must be wave-uniform (HW adds lane*16)
DEV void gl_lds16(ushort* lds_base, const ushort* gp) {
  __builtin_amdgcn_global_load_lds(
      (__attribute__((address_space(1))) const void*)gp,
      (__attribute__((address_space(3))) void*)lds_base, 16, 0, 0);
}

// ---------------- zero scalar slots ----------------
__global__ void k_zero(unsigned* p, int n) {
  int i = blockIdx.x * blockDim.x + threadIdx.x;
  if (i < n) p[i] = 0u;
}

// ------------- weight transpose fp32 W[K][N] -> bf16 WT[N][K] -------------
__global__ __launch_bounds__(256) void k_wt(const float* __restrict__ W,
                                            ushort* __restrict__ WT, int K, int N) {
  __shared__ float T[32][33];
  int k0 = blockIdx.y * 32, n0 = blockIdx.x * 32;
  int tx = threadIdx.x & 31, ty = threadIdx.x >> 5;
  for (int r = ty; r < 32; r += 8) {
    int k = k0 + r, n = n0 + tx;
    T[r][tx] = (k < K && n < N) ? W[(size_t)k * N + n] : 0.f;
  }
  __syncthreads();
  for (int r = ty; r < 32; r += 8) {
    int n = n0 + r, k = k0 + tx;
    if (n < N && k < K) WT[(size_t)n * K + k] = f2b(T[tx][r]);
  }
}

// ---------------- f32 -> bf16 elementwise ----------------
__global__ void k_cvt(const float* __restrict__ in, ushort* __restrict__ out, int n) {
  int i = blockIdx.x * 256 + threadIdx.x;
  if (i < n) out[i] = f2b(in[i]);
}

// ---------------- layernorm (C==1280), out bf16 ----------------
__global__ __launch_bounds__(256) void k_ln(const float* __restrict__ x,
    const float* __restrict__ g, const float* __restrict__ b,
    ushort* __restrict__ out) {
  const int C = 1280;
  int row = blockIdx.x, tid = threadIdx.x;
  const float* xr = x + (size_t)row * C;
  float v[5];
  float s = 0.f, ss = 0.f;
  for (int i = 0; i < 5; i++) {
    v[i] = xr[tid + i * 256];
    s += v[i]; ss += v[i] * v[i];
  }
  for (int off = 32; off; off >>= 1) {
    s += __shfl_down(s, off);
    ss += __shfl_down(ss, off);
  }
  __shared__ float red[8];
  __shared__ float mu_s, rstd_s;
  int wave = tid >> 6, lane = tid & 63;
  if (lane == 0) { red[wave] = s; red[4 + wave] = ss; }
  __syncthreads();
  if (tid == 0) {
    float S = red[0] + red[1] + red[2] + red[3];
    float SS = red[4] + red[5] + red[6] + red[7];
    float mu = S / C;
    float var = SS / C - mu * mu;
    mu_s = mu;
    rstd_s = rsqrtf(var + 1e-5f);
  }
  __syncthreads();
  float mu = mu_s, rstd = rstd_s;
  for (int i = 0; i < 5; i++) {
    int c = tid + i * 256;
    out[(size_t)row * C + c] = f2b((v[i] - mu) * rstd * g[c] + b[c]);
  }
}

// ---------------- bf16 NT GEMM: C[M,N] = A[M,K] @ BT[N,K]^T ----------------
// 128x128 tile, 4 waves (2x2 of 64x64), 16x16x32 MFMA, BK=32,
// m97-style global_load_lds staging into unpadded LDS [128][32].
__global__ __launch_bounds__(256, 2) void k_gemm(
    const ushort* __restrict__ A, int lda,
    const ushort* __restrict__ BT, int ldb,
    float* __restrict__ Cf, ushort* __restrict__ Cb, int ldc,
    const float* __restrict__ bias, const float* __restrict__ resid,
    unsigned* am_slot, int M, int N, int K) {
  __shared__ __align__(16) ushort SAB[8192];  // A[128][32] @0, B[128][32] @4096
  int tid = threadIdx.x;
  int wave = tid >> 6, lane = tid & 63;
  int q = lane >> 4, mi = lane & 15;
  int wr = (wave >> 1) * 64, wc = (wave & 1) * 64;
  int bm0 = blockIdx.y * 128, bn0 = blockIdx.x * 128;
  f32x4 acc[4][4] = {};
  for (int k0 = 0; k0 < K; k0 += 32) {
    __syncthreads();
    // 1024 16B-chunks: waves 0,1 stage A (512 chunks), waves 2,3 stage B.
    for (int t = 0; t < 4; t++) {
      int c = wave * 256 + t * 64 + lane;
      const ushort* gp;
      if (c < 512) {
        int r = c >> 2, kc = (c & 3) << 3;
        int gr = bm0 + r; if (gr >= M) gr = M - 1;
        gp = A + (size_t)gr * lda + k0 + kc;
      } else {
        int c2 = c - 512;
        int r = c2 >> 2, kc = (c2 & 3) << 3;
        int gn = bn0 + r; if (gn >= N) gn = N - 1;
        gp = BT + (size_t)gn * ldb + k0 + kc;
      }
      gl_lds16(&SAB[(wave * 256 + t * 64) * 8], gp);
    }
    __syncthreads();
    bf16x8 af[4], bfr[4];
    for (int i = 0; i < 4; i++) {
      af[i]  = *(const bf16x8*)&SAB[(wr + i * 16 + mi) * 32 + q * 8];
      bfr[i] = *(const bf16x8*)&SAB[4096 + (wc + i * 16 + mi) * 32 + q * 8];
    }
    for (int i = 0; i < 4; i++)
      for (int j = 0; j < 4; j++)
        acc[i][j] = __builtin_amdgcn_mfma_f32_16x16x32_bf16(af[i], bfr[j], acc[i][j], 0, 0, 0);
  }
  float am = 0.f;
  for (int i = 0; i < 4; i++)
    for (int j = 0; j < 4; j++)
      for (int reg = 0; reg < 4; reg++) {
        int r_ = bm0 + wr + i * 16 + q * 4 + reg;
        int c_ = bn0 + wc + j * 16 + mi;
        float v = acc[i][j][reg];
        am = fmaxf(am, fabsf(v));
        if (r_ < M && c_ < N) {
          if (bias) v += bias[c_];
          if (resid) v += resid[(size_t)r_ * ldc + c_];
          if (Cf) Cf[(size_t)r_ * ldc + c_] = v;
          if (Cb) Cb[(size_t)r_ * ldc + c_] = f2b(v);
        }
      }
  if (am_slot) {
    for (int off = 32; off; off >>= 1) am = fmaxf(am, __shfl_down(am, off));
    if (lane == 0) atomicMax(am_slot, __float_as_uint(am));
  }
}

// ---------------- symmetric fake-quant, in-place on bf16 ----------------
__global__ void k_quant(const ushort* __restrict__ in, ushort* __restrict__ out,
                        const unsigned* __restrict__ slot, int n) {
  int i = blockIdx.x * 256 + threadIdx.x;
  if (i >= n) return;
  float delta = fmaxf(__uint_as_float(*slot), 1e-8f) * (1.f / 127.f);
  float x = b2f(in[i]);
  float y = fminf(fmaxf(rintf(x / delta), -128.f), 127.f) * delta;
  out[i] = f2b(y);
}

// ------- V transpose per head: vq[b*Mr+m][h*64+d] -> vT[bh][d][m] (zero-pad) -------
__global__ __launch_bounds__(256) void k_vt(const ushort* __restrict__ vq,
    ushort* __restrict__ vT, int H, int Mr, int Mpad) {
  const int C = 1280;
  __shared__ __align__(16) ushort T[64][72];
  int bh = blockIdx.y, b = bh / H, h = bh % H;
  int m0 = blockIdx.x * 64;
  int tid = threadIdx.x;
  for (int c = tid; c < 512; c += 256) {
    int mm = c >> 3, dc = (c & 7) << 3;
    int m = m0 + mm;
    int4 val = make_int4(0, 0, 0, 0);
    if (m < Mr) val = *(const int4*)(vq + ((size_t)b * Mr + m) * C + h * 64 + dc);
    *(int4*)&T[mm][dc] = val;
  }
  __syncthreads();
  for (int c = tid; c < 512; c += 256) {
    int dd = c >> 3, mc = (c & 7) << 3;
    unsigned w0 = (unsigned)T[mc + 0][dd] | ((unsigned)T[mc + 1][dd] << 16);
    unsigned w1 = (unsigned)T[mc + 2][dd] | ((unsigned)T[mc + 3][dd] << 16);
    unsigned w2 = (unsigned)T[mc + 4][dd] | ((unsigned)T[mc + 5][dd] << 16);
    unsigned w3 = (unsigned)T[mc + 6][dd] | ((unsigned)T[mc + 7][dd] << 16);
    int4 val = make_int4((int)w0, (int)w1, (int)w2, (int)w3);
    *(int4*)(vT + ((size_t)bh * 64 + dd) * Mpad + m0 + mc) = val;
  }
}

// ------- attention phase 1: per-row smax & Z, global max(1/Z) -> pmax -------
__global__ __launch_bounds__(256) void k_attn1(
    const ushort* __restrict__ qq, const ushort* __restrict__ kq,
    float2* __restrict__ rs, unsigned* __restrict__ pmax,
    int H, int N, int Mr, float scale) {
  const int C = 1280;
  __shared__ __align__(16) ushort Qs[64][72];
  __shared__ __align__(16) ushort Ks[64][72];
  __shared__ float Ss[64][68];
  __shared__ float mq4[64][4], zq4[64][4];
  int tid = threadIdx.x;
  int wave = tid >> 6, lane = tid & 63;
  int q = lane >> 4, mi = lane & 15;
  int bh = blockIdx.y, b = bh / H, h = bh % H;
  int r0 = blockIdx.x * 64;
  for (int c = tid; c < 512; c += 256) {
    int r = c >> 3, dc = (c & 7) << 3;
    *(int4*)&Qs[r][dc] = *(const int4*)(qq + ((size_t)b * N + r0 + r) * C + h * 64 + dc);
  }
  float m_run = -1e30f, z_run = 0.f;
  int row = tid >> 2, qt = tid & 3;
  int nt = (Mr + 63) >> 6;
  for (int mt = 0; mt < nt; mt++) {
    __syncthreads();
    for (int c = tid; c < 512; c += 256) {
      int mm = c >> 3, dc = (c & 7) << 3;
      int m = mt * 64 + mm;
      int4 val = make_int4(0, 0, 0, 0);
      if (m < Mr) val = *(const int4*)(kq + ((size_t)b * Mr + m) * C + h * 64 + dc);
      *(int4*)&Ks[mm][dc] = val;
    }
    __syncthreads();
    f32x4 sacc[4] = {};
    for (int kc = 0; kc < 2; kc++) {
      bf16x8 aq = *(const bf16x8*)&Qs[wave * 16 + mi][kc * 32 + q * 8];
      for (int j = 0; j < 4; j++) {
        bf16x8 bk = *(const bf16x8*)&Ks[j * 16 + mi][kc * 32 + q * 8];
        sacc[j] = __builtin_amdgcn_mfma_f32_16x16x32_bf16(aq, bk, sacc[j], 0, 0, 0);
      }
    }
    for (int j = 0; j < 4; j++)
      for (int reg = 0; reg < 4; reg++)
        Ss[wave * 16 + q * 4 + reg][j * 16 + mi] = sacc[j][reg] * scale;
    __syncthreads();
    for (int cc = 0; cc < 16; cc++) {
      int col = qt * 16 + cc;
      int mg = mt * 64 + col;
      if (mg < Mr) {
        float sv = Ss[row][col];
        if (sv <= m_run) {
          z_run += __expf(sv - m_run);
        } else {
          z_run = z_run * __expf(m_run - sv) + 1.f;
          m_run = sv;
        }
      }
    }
  }
  __syncthreads();
  mq4[row][qt] = m_run; zq4[row][qt] = z_run;
  __syncthreads();
  if (tid < 64) {
    float M_ = mq4[tid][0];
    for (int k = 1; k < 4; k++) M_ = fmaxf(M_, mq4[tid][k]);
    float Z = 0.f;
    for (int k = 0; k < 4; k++) Z += zq4[tid][k] * __expf(mq4[tid][k] - M_);
    float2 st; st.x = M_; st.y = Z;
    rs[(size_t)bh * N + r0 + tid] = st;
    float pm = 1.f / Z;
    for (int off = 32; off; off >>= 1) pm = fmaxf(pm, __shfl_down(pm, off));
    if (tid == 0) atomicMax(pmax, __float_as_uint(pm));
  }
}

// ------- attention phase 2: recompute S, quantize probs, P@V -> ao (bf16) -------
__global__ __launch_bounds__(256) void k_attn2(
    const ushort* __restrict__ qq, const ushort* __restrict__ kq,
    const ushort* __restrict__ vT, const float2* __restrict__ rs,
    const unsigned* __restrict__ pmax, ushort* __restrict__ ao,
    int H, int N, int Mr, int Mpad, float scale) {
  const int C = 1280;
  __shared__ __align__(16) ushort Qs[64][72];
  __shared__ __align__(16) ushort Ks[64][72];
  __shared__ __align__(16) ushort Vs[64][72];
  __shared__ __align__(16) ushort Ps[64][72];
  __shared__ float Ss[64][68];
  int tid = threadIdx.x;
  int wave = tid >> 6, lane = tid & 63;
  int q = lane >> 4, mi = lane & 15;
  int bh = blockIdx.y, b = bh / H, h = bh % H;
  int r0 = blockIdx.x * 64;
  for (int c = tid; c < 512; c += 256) {
    int r = c >> 3, dc = (c & 7) << 3;
    *(int4*)&Qs[r][dc] = *(const int4*)(qq + ((size_t)b * N + r0 + r) * C + h * 64 + dc);
  }
  int row = tid >> 2, qt = tid & 3;
  float2 st = rs[(size_t)bh * N + r0 + row];
  float delta = fmaxf(__uint_as_float(*pmax), 1e-8f) * (1.f / 255.f);
  float invd = 1.f / delta;
  f32x4 oacc[4] = {};
  int nt = (Mr + 63) >> 6;
  for (int mt = 0; mt < nt; mt++) {
    __syncthreads();
    for (int c = tid; c < 512; c += 256) {
      int mm = c >> 3, dc = (c & 7) << 3;
      int m = mt * 64 + mm;
      int4 val = make_int4(0, 0, 0, 0);
      if (m < Mr) val = *(const int4*)(kq + ((size_t)b * Mr + m) * C + h * 64 + dc);
      *(int4*)&Ks[mm][dc] = val;
      *(int4*)&Vs[mm][dc] = *(const int4*)(vT + ((size_t)bh * 64 + mm) * Mpad + mt * 64 + dc);
    }
    __syncthreads();
    f32x4 sacc[4] = {};
    for (int kc = 0; kc < 2; kc++) {
      bf16x8 aq = *(const bf16x8*)&Qs[wave * 16 + mi][kc * 32 + q * 8];
      for (int j = 0; j < 4; j++) {
        bf16x8 bk = *(const bf16x8*)&Ks[j * 16 + mi][kc * 32 + q * 8];
        sacc[j] = __builtin_amdgcn_mfma_f32_16x16x32_bf16(aq, bk, sacc[j], 0, 0, 0);
      }
    }
    for (int j = 0; j < 4; j++)
      for (int reg = 0; reg < 4; reg++)
        Ss[wave * 16 + q * 4 + reg][j * 16 + mi] = sacc[j][reg] * scale;
    __syncthreads();
    for (int cc = 0; cc < 16; cc++) {
      int col = qt * 16 + cc;
      int mg = mt * 64 + col;
      float p = 0.f;
      if (mg < Mr) {
        float sv = Ss[row][col];
        p = __expf(sv - st.x) / st.y;
        p = fminf(rintf(p * invd), 255.f) * delta;
      }
      Ps[row][col] = f2b(p);
    }
    __syncthreads();
    for (int kc = 0; kc < 2; kc++) {
      bf16x8 ap = *(const bf16x8*)&Ps[wave * 16 + mi][kc * 32 + q * 8];
      for (int j = 0; j < 4; j++) {
        bf16x8 bv = *(const bf16x8*)&Vs[j * 16 + mi][kc * 32 + q * 8];
        oacc[j] = __builtin_amdgcn_mfma_f32_16x16x32_bf16(ap, bv, oacc[j], 0, 0, 0);
      }
    }
  }
  for (int j = 0; j < 4; j++)
    for (int reg = 0; reg < 4; reg++) {
      int r_ = r0 + wave * 16 + q * 4 + reg;
      int d_ = j * 16 + mi;
      ao[((size_t)b * N + r_) * C + h * 64 + d_] = f2b(oacc[j][reg]);
    }
}

// ------- fused FF1 + GEGLU: GG[r][c] = (A@W)[r][c]+b * gelu((A@W)[r][c+5120]+b) -------
// 128(M)x64(N) tile for BOTH halves -> 64 acc floats/thread (no spill).
__global__ __launch_bounds__(256, 2) void k_ff1(
    const ushort* __restrict__ A,          // LN [8192][1280]
    const ushort* __restrict__ BT,         // WF1T [10240][1280]
    const float* __restrict__ bias,        // bff1 [10240]
    ushort* __restrict__ GG) {             // [8192][5120]
  const int K = 1280;
  __shared__ __align__(16) ushort SAB[8192]; // A[128][32]@0, Ba[64][32]@4096, Bg[64][32]@6144
  int tid = threadIdx.x;
  int wave = tid >> 6, lane = tid & 63;
  int q = lane >> 4, mi = lane & 15;
  int wr = (wave >> 1) * 64, wc = (wave & 1) * 32;
  int bm0 = blockIdx.y * 128, bn0 = blockIdx.x * 64;
  f32x4 acca[4][2] = {}, accg[4][2] = {};
  for (int k0 = 0; k0 < K; k0 += 32) {
    __syncthreads();
    // waves 0,1: A (512 chunks); wave 2: Ba (256); wave 3: Bg (256)
    for (int t = 0; t < 4; t++) {
      int c = wave * 256 + t * 64 + lane;
      const ushort* gp;
      if (c < 512) {
        int r = c >> 2, kc = (c & 3) << 3;
        gp = A + (size_t)(bm0 + r) * K + k0 + kc;
      } else if (c < 768) {
        int c2 = c - 512; int r = c2 >> 2, kc = (c2 & 3) << 3;
        gp = BT + (size_t)(bn0 + r) * K + k0 + kc;
      } else {
        int c2 = c - 768; int r = c2 >> 2, kc = (c2 & 3) << 3;
        gp = BT + (size_t)(5120 + bn0 + r) * K + k0 + kc;
      }
      gl_lds16(&SAB[(wave * 256 + t * 64) * 8], gp);
    }
    __syncthreads();
    bf16x8 af[4], bar[2], bgr[2];
    for (int i = 0; i < 4; i++)
      af[i] = *(const bf16x8*)&SAB[(wr + i * 16 + mi) * 32 + q * 8];
    for (int j = 0; j < 2; j++) {
      bar[j] = *(const bf16x8*)&SAB[4096 + (wc + j * 16 + mi) * 32 + q * 8];
      bgr[j] = *(const bf16x8*)&SAB[6144 + (wc + j * 16 + mi) * 32 + q * 8];
    }
    for (int i = 0; i < 4; i++)
      for (int j = 0; j < 2; j++) {
        acca[i][j] = __builtin_amdgcn_mfma_f32_16x16x32_bf16(af[i], bar[j], acca[i][j], 0, 0, 0);
        accg[i][j] = __builtin_amdgcn_mfma_f32_16x16x32_bf16(af[i], bgr[j], accg[i][j], 0, 0, 0);
      }
  }
  for (int i = 0; i < 4; i++)
    for (int j = 0; j < 2; j++)
      for (int reg = 0; reg < 4; reg++) {
        int r_ = bm0 + wr + i * 16 + q * 4 + reg;
        int c_ = bn0 + wc + j * 16 + mi;
        float a = acca[i][j][reg] + bias[c_];
        float g = accg[i][j][reg] + bias[5120 + c_];
        float y = 0.7978845608028654f * (g + 0.044715f * g * g * g);
        float gel = 0.5f * g * (1.f + tanhf(y));
        GG[(size_t)r_ * 5120 + c_] = f2b(a * gel);
      }
}

extern "C" void kernel_launch(void* const* d_in, const int* in_sizes, int n_in,
                              void* d_out, int out_size, void* d_ws, size_t ws_size,
                              hipStream_t stream) {
  const float* x_in = (const float*)d_in[0];
  const float* ctx  = (const float*)d_in[1];
  const float* ln1g = (const float*)d_in[2];
  const float* ln1b = (const float*)d_in[3];
  const float* ln2g = (const float*)d_in[4];
  const float* ln2b = (const float*)d_in[5];
  const float* ln3g = (const float*)d_in[6];
  const float* ln3b = (const float*)d_in[7];
  const float* Wq1  = (const float*)d_in[8];
  const float* Wk1  = (const float*)d_in[9];
  const float* Wv1  = (const float*)d_in[10];
  const float* Wo1  = (const float*)d_in[11];
  const float* bo1  = (const float*)d_in[12];
  const float* Wq2  = (const float*)d_in[13];
  const float* Wk2  = (const float*)d_in[14];
  const float* Wv2  = (const float*)d_in[15];
  const float* Wo2  = (const float*)d_in[16];
  const float* bo2  = (const float*)d_in[17];
  const float* Wff1 = (const float*)d_in[18];
  const float* bff1 = (const float*)d_in[19];
  const float* Wff2 = (const float*)d_in[20];
  const float* bff2 = (const float*)d_in[21];
  float* out = (float*)d_out;   // also doubles as the fp32 residual stream "xcur"

  const int NR = 8192;   // B*N
  const int C = 1280, H = 20, Nseq = 1024, CC = 768;
  const int MR2 = 616;   // B*M (cross rows)

  char* ws = (char*)d_ws;
  size_t off = 0;
  auto alloc = [&](size_t bytes) -> void* {
    void* p = ws + off;
    off += (bytes + 255) & ~(size_t)255;
    return p;
  };
  unsigned* scal = (unsigned*)alloc(64);
  ushort* Wq1T  = (ushort*)alloc((size_t)C * C * 2);
  ushort* Wk1T  = (ushort*)alloc((size_t)C * C * 2);
  ushort* Wv1T  = (ushort*)alloc((size_t)C * C * 2);
  ushort* Wo1T  = (ushort*)alloc((size_t)C * C * 2);
  ushort* Wq2T  = (ushort*)alloc((size_t)C * C * 2);
  ushort* Wk2T  = (ushort*)alloc((size_t)C * CC * 2);
  ushort* Wv2T  = (ushort*)alloc((size_t)C * CC * 2);
  ushort* Wo2T  = (ushort*)alloc((size_t)C * C * 2);
  ushort* WF1T  = (ushort*)alloc((size_t)10240 * C * 2);
  ushort* WF2T  = (ushort*)alloc((size_t)C * 5120 * 2);
  ushort* LN    = (ushort*)alloc((size_t)NR * C * 2);
  size_t regionR = off;  // attention region; stage-3 GG overlays it
  ushort* QQ    = (ushort*)alloc((size_t)NR * C * 2);
  ushort* KQ    = (ushort*)alloc((size_t)NR * C * 2);
  ushort* VQ    = (ushort*)alloc((size_t)NR * C * 2);  // also AO after k_vt
  ushort* VT    = (ushort*)alloc((size_t)160 * 64 * 1024 * 2);
  float2* RS    = (float2*)alloc((size_t)160 * 1024 * 8);
  ushort* CTXB  = (ushort*)alloc((size_t)MR2 * CC * 2);
  size_t need = off;
  ushort* AO = VQ;                       // alias: VQ dead once VT is built
  ushort* GG = (ushort*)(ws + regionR);  // 84 MB, overlays QQ..VT in stage 3
  if (ws_size < need) return;  // diagnostic: absmax==poison => ws too small

  // --- init & weight prep ---
  k_zero<<<1, 64, 0, stream>>>(scal, 8);
  k_wt<<<dim3(40, 40), 256, 0, stream>>>(Wq1, Wq1T, C, C);
  k_wt<<<dim3(40, 40), 256, 0, stream>>>(Wk1, Wk1T, C, C);
  k_wt<<<dim3(40, 40), 256, 0, stream>>>(Wv1, Wv1T, C, C);
  k_wt<<<dim3(40, 40), 256, 0, stream>>>(Wo1, Wo1T, C, C);
  k_wt<<<dim3(40, 40), 256, 0, stream>>>(Wq2, Wq2T, C, C);
  k_wt<<<dim3(40, 24), 256, 0, stream>>>(Wk2, Wk2T, CC, C);
  k_wt<<<dim3(40, 24), 256, 0, stream>>>(Wv2, Wv2T, CC, C);
  k_wt<<<dim3(40, 40), 256, 0, stream>>>(Wo2, Wo2T, C, C);
  k_wt<<<dim3(320, 40), 256, 0, stream>>>(Wff1, WF1T, C, 10240);
  k_wt<<<dim3(40, 160), 256, 0, stream>>>(Wff2, WF2T, 5120, C);

  // ================= stage 1: self-attention =================
  k_ln<<<NR, 256, 0, stream>>>(x_in, ln1g, ln1b, LN);
  k_gemm<<<dim3(10, 64), 256, 0, stream>>>(LN, C, Wq1T, C, nullptr, QQ, C,
                                           nullptr, nullptr, scal + 0, NR, C, C);
  k_quant<<<(NR * C + 255) / 256, 256, 0, stream>>>(QQ, QQ, scal + 0, NR * C);
  k_gemm<<<dim3(10, 64), 256, 0, stream>>>(LN, C, Wk1T, C, nullptr, KQ, C,
                                           nullptr, nullptr, scal + 1, NR, C, C);
  k_quant<<<(NR * C + 255) / 256, 256, 0, stream>>>(KQ, KQ, scal + 1, NR * C);
  k_gemm<<<dim3(10, 64), 256, 0, stream>>>(LN, C, Wv1T, C, nullptr, VQ, C,
                                           nullptr, nullptr, scal + 2, NR, C, C);
  k_quant<<<(NR * C + 255) / 256, 256, 0, stream>>>(VQ, VQ, scal + 2, NR * C);
  k_vt<<<dim3(16, 160), 256, 0, stream>>>(VQ, VT, H, 1024, 1024);
  k_attn1<<<dim3(16, 160), 256, 0, stream>>>(QQ, KQ, RS, scal + 3, H, Nseq, 1024, 0.125f);
  k_attn2<<<dim3(16, 160), 256, 0, stream>>>(QQ, KQ, VT, RS, scal + 3, AO,
                                             H, Nseq, 1024, 1024, 0.125f);
  k_gemm<<<dim3(10, 64), 256, 0, stream>>>(AO, C, Wo1T, C, out, nullptr, C,
                                           bo1, x_in, nullptr, NR, C, C);

  // ================= stage 2: cross-attention =================
  k_ln<<<NR, 256, 0, stream>>>(out, ln2g, ln2b, LN);
  k_gemm<<<dim3(10, 64), 256, 0, stream>>>(LN, C, Wq2T, C, nullptr, QQ, C,
                                           nullptr, nullptr, scal + 4, NR, C, C);
  k_quant<<<(NR * C + 255) / 256, 256, 0, stream>>>(QQ, QQ, scal + 4, NR * C);
  k_cvt<<<(MR2 * CC + 255) / 256, 256, 0, stream>>>(ctx, CTXB, MR2 * CC);
  k_gemm<<<dim3(10, 5), 256, 0, stream>>>(CTXB, CC, Wk2T, CC, nullptr, KQ, C,
                                          nullptr, nullptr, scal + 5, MR2, C, CC);
  k_quant<<<(MR2 * C + 255) / 256, 256, 0, stream>>>(KQ, KQ, scal + 5, MR2 * C);
  k_gemm<<<dim3(10, 5), 256, 0, stream>>>(CTXB, CC, Wv2T, CC, nullptr, VQ, C,
                                          nullptr, nullptr, scal + 6, MR2, C, CC);
  k_quant<<<(MR2 * C + 255) / 256, 256, 0, stream>>>(VQ, VQ, scal + 6, MR2 * C);
  k_vt<<<dim3(2, 160), 256, 0, stream>>>(VQ, VT, H, 77, 128);
  k_attn1<<<dim3(16, 160), 256, 0, stream>>>(QQ, KQ, RS, scal + 7, H, Nseq, 77, 0.125f);
  k_attn2<<<dim3(16, 160), 256, 0, stream>>>(QQ, KQ, VT, RS, scal + 7, AO,
                                             H, Nseq, 77, 128, 0.125f);
  k_gemm<<<dim3(10, 64), 256, 0, stream>>>(AO, C, Wo2T, C, out, nullptr, C,
                                           bo2, out, nullptr, NR, C, C);

  // ================= stage 3: GEGLU FF (fused, no H1 materialization) =================
  k_ln<<<NR, 256, 0, stream>>>(out, ln3g, ln3b, LN);
  k_ff1<<<dim3(80, 64), 256, 0, stream>>>(LN, WF1T, bff1, GG);
  k_gemm<<<dim3(10, 64), 256, 0, stream>>>(GG, 5120, WF2T, 5120, out, nullptr, C,
                                           bff2, out, nullptr, NR, C, 5120);
}

// Round 4
// 7214.493 us; speedup vs baseline: 1.5464x; 1.0147x over previous
//
#include <hip/hip_runtime.h>

typedef __attribute__((ext_vector_type(8))) short bf16x8;
typedef __attribute__((ext_vector_type(4))) float f32x4;

#define DEV __device__ __forceinline__

DEV ushort f2b(float f) {
  unsigned u = __float_as_uint(f);
  u += 0x7fffu + ((u >> 16) & 1u);   // RNE to bf16
  return (ushort)(u >> 16);
}
DEV float b2f(ushort u) { return __uint_as_float(((unsigned)u) << 16); }

// async global->LDS, 16B per lane; lds base must be wave-uniform (HW adds lane*16)
DEV void gl_lds16(ushort* lds_base, const ushort* gp) {
  __builtin_amdgcn_global_load_lds(
      (__attribute__((address_space(1))) const void*)gp,
      (__attribute__((address_space(3))) void*)lds_base, 16, 0, 0);
}

// ---------------- zero scalar slots ----------------
__global__ void k_zero(unsigned* p, int n) {
  int i = blockIdx.x * blockDim.x + threadIdx.x;
  if (i < n) p[i] = 0u;
}

// ------------- weight transpose fp32 W[K][N] -> bf16 WT[N][K] -------------
__global__ __launch_bounds__(256) void k_wt(const float* __restrict__ W,
                                            ushort* __restrict__ WT, int K, int N) {
  __shared__ float T[32][33];
  int k0 = blockIdx.y * 32, n0 = blockIdx.x * 32;
  int tx = threadIdx.x & 31, ty = threadIdx.x >> 5;
  for (int r = ty; r < 32; r += 8) {
    int k = k0 + r, n = n0 + tx;
    T[r][tx] = (k < K && n < N) ? W[(size_t)k * N + n] : 0.f;
  }
  __syncthreads();
  for (int r = ty; r < 32; r += 8) {
    int n = n0 + r, k = k0 + tx;
    if (n < N && k < K) WT[(size_t)n * K + k] = f2b(T[tx][r]);
  }
}

// ---------------- f32 -> bf16 elementwise ----------------
__global__ void k_cvt(const float* __restrict__ in, ushort* __restrict__ out, int n) {
  int i = blockIdx.x * 256 + threadIdx.x;
  if (i < n) out[i] = f2b(in[i]);
}

// ---------------- layernorm (C==1280), out bf16 ----------------
__global__ __launch_bounds__(256) void k_ln(const float* __restrict__ x,
    const float* __restrict__ g, const float* __restrict__ b,
    ushort* __restrict__ out) {
  const int C = 1280;
  int row = blockIdx.x, tid = threadIdx.x;
  const float* xr = x + (size_t)row * C;
  float v[5];
  float s = 0.f, ss = 0.f;
  for (int i = 0; i < 5; i++) {
    v[i] = xr[tid + i * 256];
    s += v[i]; ss += v[i] * v[i];
  }
  for (int off = 32; off; off >>= 1) {
    s += __shfl_down(s, off);
    ss += __shfl_down(ss, off);
  }
  __shared__ float red[8];
  __shared__ float mu_s, rstd_s;
  int wave = tid >> 6, lane = tid & 63;
  if (lane == 0) { red[wave] = s; red[4 + wave] = ss; }
  __syncthreads();
  if (tid == 0) {
    float S = red[0] + red[1] + red[2] + red[3];
    float SS = red[4] + red[5] + red[6] + red[7];
    float mu = S / C;
    float var = SS / C - mu * mu;
    mu_s = mu;
    rstd_s = rsqrtf(var + 1e-5f);
  }
  __syncthreads();
  float mu = mu_s, rstd = rstd_s;
  for (int i = 0; i < 5; i++) {
    int c = tid + i * 256;
    out[(size_t)row * C + c] = f2b((v[i] - mu) * rstd * g[c] + b[c]);
  }
}

// ---------------- bf16 NT GEMM: C[M,N] = A[M,K] @ BT[N,K]^T ----------------
// 128x128 tile, 4 waves (2x2 of 64x64), 16x16x32 MFMA, BK=32,
// m97-style global_load_lds staging into unpadded LDS [128][32].
// NOTE: no second launch_bounds arg — (256,2) capped VGPRs at 32 and spilled
// the accumulators to scratch (measured: 6.7 GB WRITE_SIZE on FF2).
__global__ __launch_bounds__(256) void k_gemm(
    const ushort* __restrict__ A, int lda,
    const ushort* __restrict__ BT, int ldb,
    float* __restrict__ Cf, ushort* __restrict__ Cb, int ldc,
    const float* __restrict__ bias, const float* __restrict__ resid,
    unsigned* am_slot, int M, int N, int K) {
  __shared__ __align__(16) ushort SAB[8192];  // A[128][32] @0, B[128][32] @4096
  int tid = threadIdx.x;
  int wave = tid >> 6, lane = tid & 63;
  int q = lane >> 4, mi = lane & 15;
  int wr = (wave >> 1) * 64, wc = (wave & 1) * 64;
  int bm0 = blockIdx.y * 128, bn0 = blockIdx.x * 128;
  f32x4 acc[4][4] = {};
  for (int k0 = 0; k0 < K; k0 += 32) {
    __syncthreads();
    // 1024 16B-chunks: waves 0,1 stage A (512 chunks), waves 2,3 stage B.
    for (int t = 0; t < 4; t++) {
      int c = wave * 256 + t * 64 + lane;
      const ushort* gp;
      if (c < 512) {
        int r = c >> 2, kc = (c & 3) << 3;
        int gr = bm0 + r; if (gr >= M) gr = M - 1;
        gp = A + (size_t)gr * lda + k0 + kc;
      } else {
        int c2 = c - 512;
        int r = c2 >> 2, kc = (c2 & 3) << 3;
        int gn = bn0 + r; if (gn >= N) gn = N - 1;
        gp = BT + (size_t)gn * ldb + k0 + kc;
      }
      gl_lds16(&SAB[(wave * 256 + t * 64) * 8], gp);
    }
    __syncthreads();
    bf16x8 af[4], bfr[4];
    for (int i = 0; i < 4; i++) {
      af[i]  = *(const bf16x8*)&SAB[(wr + i * 16 + mi) * 32 + q * 8];
      bfr[i] = *(const bf16x8*)&SAB[4096 + (wc + i * 16 + mi) * 32 + q * 8];
    }
    for (int i = 0; i < 4; i++)
      for (int j = 0; j < 4; j++)
        acc[i][j] = __builtin_amdgcn_mfma_f32_16x16x32_bf16(af[i], bfr[j], acc[i][j], 0, 0, 0);
  }
  float am = 0.f;
  for (int i = 0; i < 4; i++)
    for (int j = 0; j < 4; j++)
      for (int reg = 0; reg < 4; reg++) {
        int r_ = bm0 + wr + i * 16 + q * 4 + reg;
        int c_ = bn0 + wc + j * 16 + mi;
        float v = acc[i][j][reg];
        am = fmaxf(am, fabsf(v));
        if (r_ < M && c_ < N) {
          if (bias) v += bias[c_];
          if (resid) v += resid[(size_t)r_ * ldc + c_];
          if (Cf) Cf[(size_t)r_ * ldc + c_] = v;
          if (Cb) Cb[(size_t)r_ * ldc + c_] = f2b(v);
        }
      }
  if (am_slot) {
    for (int off = 32; off; off >>= 1) am = fmaxf(am, __shfl_down(am, off));
    if (lane == 0) atomicMax(am_slot, __float_as_uint(am));
  }
}

// ---------------- symmetric fake-quant, in-place on bf16 ----------------
__global__ void k_quant(const ushort* __restrict__ in, ushort* __restrict__ out,
                        const unsigned* __restrict__ slot, int n) {
  int i = blockIdx.x * 256 + threadIdx.x;
  if (i >= n) return;
  float delta = fmaxf(__uint_as_float(*slot), 1e-8f) * (1.f / 127.f);
  float x = b2f(in[i]);
  float y = fminf(fmaxf(rintf(x / delta), -128.f), 127.f) * delta;
  out[i] = f2b(y);
}

// ------- V transpose per head: vq[b*Mr+m][h*64+d] -> vT[bh][d][m] (zero-pad) -------
__global__ __launch_bounds__(256) void k_vt(const ushort* __restrict__ vq,
    ushort* __restrict__ vT, int H, int Mr, int Mpad) {
  const int C = 1280;
  __shared__ __align__(16) ushort T[64][72];
  int bh = blockIdx.y, b = bh / H, h = bh % H;
  int m0 = blockIdx.x * 64;
  int tid = threadIdx.x;
  for (int c = tid; c < 512; c += 256) {
    int mm = c >> 3, dc = (c & 7) << 3;
    int m = m0 + mm;
    int4 val = make_int4(0, 0, 0, 0);
    if (m < Mr) val = *(const int4*)(vq + ((size_t)b * Mr + m) * C + h * 64 + dc);
    *(int4*)&T[mm][dc] = val;
  }
  __syncthreads();
  for (int c = tid; c < 512; c += 256) {
    int dd = c >> 3, mc = (c & 7) << 3;
    unsigned w0 = (unsigned)T[mc + 0][dd] | ((unsigned)T[mc + 1][dd] << 16);
    unsigned w1 = (unsigned)T[mc + 2][dd] | ((unsigned)T[mc + 3][dd] << 16);
    unsigned w2 = (unsigned)T[mc + 4][dd] | ((unsigned)T[mc + 5][dd] << 16);
    unsigned w3 = (unsigned)T[mc + 6][dd] | ((unsigned)T[mc + 7][dd] << 16);
    int4 val = make_int4((int)w0, (int)w1, (int)w2, (int)w3);
    *(int4*)(vT + ((size_t)bh * 64 + dd) * Mpad + m0 + mc) = val;
  }
}

// ------- attention phase 1: per-row smax & Z, global max(1/Z) -> pmax -------
__global__ __launch_bounds__(256) void k_attn1(
    const ushort* __restrict__ qq, const ushort* __restrict__ kq,
    float2* __restrict__ rs, unsigned* __restrict__ pmax,
    int H, int N, int Mr, float scale) {
  const int C = 1280;
  __shared__ __align__(16) ushort Qs[64][72];
  __shared__ __align__(16) ushort Ks[64][72];
  __shared__ float Ss[64][68];
  __shared__ float mq4[64][4], zq4[64][4];
  int tid = threadIdx.x;
  int wave = tid >> 6, lane = tid & 63;
  int q = lane >> 4, mi = lane & 15;
  int bh = blockIdx.y, b = bh / H, h = bh % H;
  int r0 = blockIdx.x * 64;
  for (int c = tid; c < 512; c += 256) {
    int r = c >> 3, dc = (c & 7) << 3;
    *(int4*)&Qs[r][dc] = *(const int4*)(qq + ((size_t)b * N + r0 + r) * C + h * 64 + dc);
  }
  float m_run = -1e30f, z_run = 0.f;
  int row = tid >> 2, qt = tid & 3;
  int nt = (Mr + 63) >> 6;
  for (int mt = 0; mt < nt; mt++) {
    __syncthreads();
    for (int c = tid; c < 512; c += 256) {
      int mm = c >> 3, dc = (c & 7) << 3;
      int m = mt * 64 + mm;
      int4 val = make_int4(0, 0, 0, 0);
      if (m < Mr) val = *(const int4*)(kq + ((size_t)b * Mr + m) * C + h * 64 + dc);
      *(int4*)&Ks[mm][dc] = val;
    }
    __syncthreads();
    f32x4 sacc[4] = {};
    for (int kc = 0; kc < 2; kc++) {
      bf16x8 aq = *(const bf16x8*)&Qs[wave * 16 + mi][kc * 32 + q * 8];
      for (int j = 0; j < 4; j++) {
        bf16x8 bk = *(const bf16x8*)&Ks[j * 16 + mi][kc * 32 + q * 8];
        sacc[j] = __builtin_amdgcn_mfma_f32_16x16x32_bf16(aq, bk, sacc[j], 0, 0, 0);
      }
    }
    for (int j = 0; j < 4; j++)
      for (int reg = 0; reg < 4; reg++)
        Ss[wave * 16 + q * 4 + reg][j * 16 + mi] = sacc[j][reg] * scale;
    __syncthreads();
    for (int cc = 0; cc < 16; cc++) {
      int col = qt * 16 + cc;
      int mg = mt * 64 + col;
      if (mg < Mr) {
        float sv = Ss[row][col];
        if (sv <= m_run) {
          z_run += __expf(sv - m_run);
        } else {
          z_run = z_run * __expf(m_run - sv) + 1.f;
          m_run = sv;
        }
      }
    }
  }
  __syncthreads();
  mq4[row][qt] = m_run; zq4[row][qt] = z_run;
  __syncthreads();
  if (tid < 64) {
    float M_ = mq4[tid][0];
    for (int k = 1; k < 4; k++) M_ = fmaxf(M_, mq4[tid][k]);
    float Z = 0.f;
    for (int k = 0; k < 4; k++) Z += zq4[tid][k] * __expf(mq4[tid][k] - M_);
    float2 st; st.x = M_; st.y = Z;
    rs[(size_t)bh * N + r0 + tid] = st;
    float pm = 1.f / Z;
    for (int off = 32; off; off >>= 1) pm = fmaxf(pm, __shfl_down(pm, off));
    if (tid == 0) atomicMax(pmax, __float_as_uint(pm));
  }
}

// ------- attention phase 2: recompute S, quantize probs, P@V -> ao (bf16) -------
__global__ __launch_bounds__(256) void k_attn2(
    const ushort* __restrict__ qq, const ushort* __restrict__ kq,
    const ushort* __restrict__ vT, const float2* __restrict__ rs,
    const unsigned* __restrict__ pmax, ushort* __restrict__ ao,
    int H, int N, int Mr, int Mpad, float scale) {
  const int C = 1280;
  __shared__ __align__(16) ushort Qs[64][72];
  __shared__ __align__(16) ushort Ks[64][72];
  __shared__ __align__(16) ushort Vs[64][72];
  __shared__ __align__(16) ushort Ps[64][72];
  __shared__ float Ss[64][68];
  int tid = threadIdx.x;
  int wave = tid >> 6, lane = tid & 63;
  int q = lane >> 4, mi = lane & 15;
  int bh = blockIdx.y, b = bh / H, h = bh % H;
  int r0 = blockIdx.x * 64;
  for (int c = tid; c < 512; c += 256) {
    int r = c >> 3, dc = (c & 7) << 3;
    *(int4*)&Qs[r][dc] = *(const int4*)(qq + ((size_t)b * N + r0 + r) * C + h * 64 + dc);
  }
  int row = tid >> 2, qt = tid & 3;
  float2 st = rs[(size_t)bh * N + r0 + row];
  float delta = fmaxf(__uint_as_float(*pmax), 1e-8f) * (1.f / 255.f);
  float invd = 1.f / delta;
  f32x4 oacc[4] = {};
  int nt = (Mr + 63) >> 6;
  for (int mt = 0; mt < nt; mt++) {
    __syncthreads();
    for (int c = tid; c < 512; c += 256) {
      int mm = c >> 3, dc = (c & 7) << 3;
      int m = mt * 64 + mm;
      int4 val = make_int4(0, 0, 0, 0);
      if (m < Mr) val = *(const int4*)(kq + ((size_t)b * Mr + m) * C + h * 64 + dc);
      *(int4*)&Ks[mm][dc] = val;
      *(int4*)&Vs[mm][dc] = *(const int4*)(vT + ((size_t)bh * 64 + mm) * Mpad + mt * 64 + dc);
    }
    __syncthreads();
    f32x4 sacc[4] = {};
    for (int kc = 0; kc < 2; kc++) {
      bf16x8 aq = *(const bf16x8*)&Qs[wave * 16 + mi][kc * 32 + q * 8];
      for (int j = 0; j < 4; j++) {
        bf16x8 bk = *(const bf16x8*)&Ks[j * 16 + mi][kc * 32 + q * 8];
        sacc[j] = __builtin_amdgcn_mfma_f32_16x16x32_bf16(aq, bk, sacc[j], 0, 0, 0);
      }
    }
    for (int j = 0; j < 4; j++)
      for (int reg = 0; reg < 4; reg++)
        Ss[wave * 16 + q * 4 + reg][j * 16 + mi] = sacc[j][reg] * scale;
    __syncthreads();
    for (int cc = 0; cc < 16; cc++) {
      int col = qt * 16 + cc;
      int mg = mt * 64 + col;
      float p = 0.f;
      if (mg < Mr) {
        float sv = Ss[row][col];
        p = __expf(sv - st.x) / st.y;
        p = fminf(rintf(p * invd), 255.f) * delta;
      }
      Ps[row][col] = f2b(p);
    }
    __syncthreads();
    for (int kc = 0; kc < 2; kc++) {
      bf16x8 ap = *(const bf16x8*)&Ps[wave * 16 + mi][kc * 32 + q * 8];
      for (int j = 0; j < 4; j++) {
        bf16x8 bv = *(const bf16x8*)&Vs[j * 16 + mi][kc * 32 + q * 8];
        oacc[j] = __builtin_amdgcn_mfma_f32_16x16x32_bf16(ap, bv, oacc[j], 0, 0, 0);
      }
    }
  }
  for (int j = 0; j < 4; j++)
    for (int reg = 0; reg < 4; reg++) {
      int r_ = r0 + wave * 16 + q * 4 + reg;
      int d_ = j * 16 + mi;
      ao[((size_t)b * N + r_) * C + h * 64 + d_] = f2b(oacc[j][reg]);
    }
}

// ------- fused FF1 + GEGLU: GG[r][c] = (A@W)[r][c]+b * gelu((A@W)[r][c+5120]+b) -------
// 128(M)x64(N) tile for BOTH halves -> 64 acc floats/thread.
__global__ __launch_bounds__(256) void k_ff1(
    const ushort* __restrict__ A,          // LN [8192][1280]
    const ushort* __restrict__ BT,         // WF1T [10240][1280]
    const float* __restrict__ bias,        // bff1 [10240]
    ushort* __restrict__ GG) {             // [8192][5120]
  const int K = 1280;
  __shared__ __align__(16) ushort SAB[8192]; // A[128][32]@0, Ba[64][32]@4096, Bg[64][32]@6144
  int tid = threadIdx.x;
  int wave = tid >> 6, lane = tid & 63;
  int q = lane >> 4, mi = lane & 15;
  int wr = (wave >> 1) * 64, wc = (wave & 1) * 32;
  int bm0 = blockIdx.y * 128, bn0 = blockIdx.x * 64;
  f32x4 acca[4][2] = {}, accg[4][2] = {};
  for (int k0 = 0; k0 < K; k0 += 32) {
    __syncthreads();
    // waves 0,1: A (512 chunks); wave 2: Ba (256); wave 3: Bg (256)
    for (int t = 0; t < 4; t++) {
      int c = wave * 256 + t * 64 + lane;
      const ushort* gp;
      if (c < 512) {
        int r = c >> 2, kc = (c & 3) << 3;
        gp = A + (size_t)(bm0 + r) * K + k0 + kc;
      } else if (c < 768) {
        int c2 = c - 512; int r = c2 >> 2, kc = (c2 & 3) << 3;
        gp = BT + (size_t)(bn0 + r) * K + k0 + kc;
      } else {
        int c2 = c - 768; int r = c2 >> 2, kc = (c2 & 3) << 3;
        gp = BT + (size_t)(5120 + bn0 + r) * K + k0 + kc;
      }
      gl_lds16(&SAB[(wave * 256 + t * 64) * 8], gp);
    }
    __syncthreads();
    bf16x8 af[4], bar[2], bgr[2];
    for (int i = 0; i < 4; i++)
      af[i] = *(const bf16x8*)&SAB[(wr + i * 16 + mi) * 32 + q * 8];
    for (int j = 0; j < 2; j++) {
      bar[j] = *(const bf16x8*)&SAB[4096 + (wc + j * 16 + mi) * 32 + q * 8];
      bgr[j] = *(const bf16x8*)&SAB[6144 + (wc + j * 16 + mi) * 32 + q * 8];
    }
    for (int i = 0; i < 4; i++)
      for (int j = 0; j < 2; j++) {
        acca[i][j] = __builtin_amdgcn_mfma_f32_16x16x32_bf16(af[i], bar[j], acca[i][j], 0, 0, 0);
        accg[i][j] = __builtin_amdgcn_mfma_f32_16x16x32_bf16(af[i], bgr[j], accg[i][j], 0, 0, 0);
      }
  }
  for (int i = 0; i < 4; i++)
    for (int j = 0; j < 2; j++)
      for (int reg = 0; reg < 4; reg++) {
        int r_ = bm0 + wr + i * 16 + q * 4 + reg;
        int c_ = bn0 + wc + j * 16 + mi;
        float a = acca[i][j][reg] + bias[c_];
        float g = accg[i][j][reg] + bias[5120 + c_];
        float y = 0.7978845608028654f * (g + 0.044715f * g * g * g);
        float gel = 0.5f * g * (1.f + tanhf(y));
        GG[(size_t)r_ * 5120 + c_] = f2b(a * gel);
      }
}

extern "C" void kernel_launch(void* const* d_in, const int* in_sizes, int n_in,
                              void* d_out, int out_size, void* d_ws, size_t ws_size,
                              hipStream_t stream) {
  const float* x_in = (const float*)d_in[0];
  const float* ctx  = (const float*)d_in[1];
  const float* ln1g = (const float*)d_in[2];
  const float* ln1b = (const float*)d_in[3];
  const float* ln2g = (const float*)d_in[4];
  const float* ln2b = (const float*)d_in[5];
  const float* ln3g = (const float*)d_in[6];
  const float* ln3b = (const float*)d_in[7];
  const float* Wq1  = (const float*)d_in[8];
  const float* Wk1  = (const float*)d_in[9];
  const float* Wv1  = (const float*)d_in[10];
  const float* Wo1  = (const float*)d_in[11];
  const float* bo1  = (const float*)d_in[12];
  const float* Wq2  = (const float*)d_in[13];
  const float* Wk2  = (const float*)d_in[14];
  const float* Wv2  = (const float*)d_in[15];
  const float* Wo2  = (const float*)d_in[16];
  const float* bo2  = (const float*)d_in[17];
  const float* Wff1 = (const float*)d_in[18];
  const float* bff1 = (const float*)d_in[19];
  const float* Wff2 = (const float*)d_in[20];
  const float* bff2 = (const float*)d_in[21];
  float* out = (float*)d_out;   // also doubles as the fp32 residual stream "xcur"

  const int NR = 8192;   // B*N
  const int C = 1280, H = 20, Nseq = 1024, CC = 768;
  const int MR2 = 616;   // B*M (cross rows)

  char* ws = (char*)d_ws;
  size_t off = 0;
  auto alloc = [&](size_t bytes) -> void* {
    void* p = ws + off;
    off += (bytes + 255) & ~(size_t)255;
    return p;
  };
  unsigned* scal = (unsigned*)alloc(64);
  ushort* Wq1T  = (ushort*)alloc((size_t)C * C * 2);
  ushort* Wk1T  = (ushort*)alloc((size_t)C * C * 2);
  ushort* Wv1T  = (ushort*)alloc((size_t)C * C * 2);
  ushort* Wo1T  = (ushort*)alloc((size_t)C * C * 2);
  ushort* Wq2T  = (ushort*)alloc((size_t)C * C * 2);
  ushort* Wk2T  = (ushort*)alloc((size_t)C * CC * 2);
  ushort* Wv2T  = (ushort*)alloc((size_t)C * CC * 2);
  ushort* Wo2T  = (ushort*)alloc((size_t)C * C * 2);
  ushort* WF1T  = (ushort*)alloc((size_t)10240 * C * 2);
  ushort* WF2T  = (ushort*)alloc((size_t)C * 5120 * 2);
  ushort* LN    = (ushort*)alloc((size_t)NR * C * 2);
  size_t regionR = off;  // attention region; stage-3 GG overlays it
  ushort* QQ    = (ushort*)alloc((size_t)NR * C * 2);
  ushort* KQ    = (ushort*)alloc((size_t)NR * C * 2);
  ushort* VQ    = (ushort*)alloc((size_t)NR * C * 2);  // also AO after k_vt
  ushort* VT    = (ushort*)alloc((size_t)160 * 64 * 1024 * 2);
  float2* RS    = (float2*)alloc((size_t)160 * 1024 * 8);
  ushort* CTXB  = (ushort*)alloc((size_t)MR2 * CC * 2);
  size_t need = off;
  ushort* AO = VQ;                       // alias: VQ dead once VT is built
  ushort* GG = (ushort*)(ws + regionR);  // 84 MB, overlays QQ..VT in stage 3
  if (ws_size < need) return;  // diagnostic: absmax==poison => ws too small

  // --- init & weight prep ---
  k_zero<<<1, 64, 0, stream>>>(scal, 8);
  k_wt<<<dim3(40, 40), 256, 0, stream>>>(Wq1, Wq1T, C, C);
  k_wt<<<dim3(40, 40), 256, 0, stream>>>(Wk1, Wk1T, C, C);
  k_wt<<<dim3(40, 40), 256, 0, stream>>>(Wv1, Wv1T, C, C);
  k_wt<<<dim3(40, 40), 256, 0, stream>>>(Wo1, Wo1T, C, C);
  k_wt<<<dim3(40, 40), 256, 0, stream>>>(Wq2, Wq2T, C, C);
  k_wt<<<dim3(40, 24), 256, 0, stream>>>(Wk2, Wk2T, CC, C);
  k_wt<<<dim3(40, 24), 256, 0, stream>>>(Wv2, Wv2T, CC, C);
  k_wt<<<dim3(40, 40), 256, 0, stream>>>(Wo2, Wo2T, C, C);
  k_wt<<<dim3(320, 40), 256, 0, stream>>>(Wff1, WF1T, C, 10240);
  k_wt<<<dim3(40, 160), 256, 0, stream>>>(Wff2, WF2T, 5120, C);

  // ================= stage 1: self-attention =================
  k_ln<<<NR, 256, 0, stream>>>(x_in, ln1g, ln1b, LN);
  k_gemm<<<dim3(10, 64), 256, 0, stream>>>(LN, C, Wq1T, C, nullptr, QQ, C,
                                           nullptr, nullptr, scal + 0, NR, C, C);
  k_quant<<<(NR * C + 255) / 256, 256, 0, stream>>>(QQ, QQ, scal + 0, NR * C);
  k_gemm<<<dim3(10, 64), 256, 0, stream>>>(LN, C, Wk1T, C, nullptr, KQ, C,
                                           nullptr, nullptr, scal + 1, NR, C, C);
  k_quant<<<(NR * C + 255) / 256, 256, 0, stream>>>(KQ, KQ, scal + 1, NR * C);
  k_gemm<<<dim3(10, 64), 256, 0, stream>>>(LN, C, Wv1T, C, nullptr, VQ, C,
                                           nullptr, nullptr, scal + 2, NR, C, C);
  k_quant<<<(NR * C + 255) / 256, 256, 0, stream>>>(VQ, VQ, scal + 2, NR * C);
  k_vt<<<dim3(16, 160), 256, 0, stream>>>(VQ, VT, H, 1024, 1024);
  k_attn1<<<dim3(16, 160), 256, 0, stream>>>(QQ, KQ, RS, scal + 3, H, Nseq, 1024, 0.125f);
  k_attn2<<<dim3(16, 160), 256, 0, stream>>>(QQ, KQ, VT, RS, scal + 3, AO,
                                             H, Nseq, 1024, 1024, 0.125f);
  k_gemm<<<dim3(10, 64), 256, 0, stream>>>(AO, C, Wo1T, C, out, nullptr, C,
                                           bo1, x_in, nullptr, NR, C, C);

  // ================= stage 2: cross-attention =================
  k_ln<<<NR, 256, 0, stream>>>(out, ln2g, ln2b, LN);
  k_gemm<<<dim3(10, 64), 256, 0, stream>>>(LN, C, Wq2T, C, nullptr, QQ, C,
                                           nullptr, nullptr, scal + 4, NR, C, C);
  k_quant<<<(NR * C + 255) / 256, 256, 0, stream>>>(QQ, QQ, scal + 4, NR * C);
  k_cvt<<<(MR2 * CC + 255) / 256, 256, 0, stream>>>(ctx, CTXB, MR2 * CC);
  k_gemm<<<dim3(10, 5), 256, 0, stream>>>(CTXB, CC, Wk2T, CC, nullptr, KQ, C,
                                          nullptr, nullptr, scal + 5, MR2, C, CC);
  k_quant<<<(MR2 * C + 255) / 256, 256, 0, stream>>>(KQ, KQ, scal + 5, MR2 * C);
  k_gemm<<<dim3(10, 5), 256, 0, stream>>>(CTXB, CC, Wv2T, CC, nullptr, VQ, C,
                                          nullptr, nullptr, scal + 6, MR2, C, CC);
  k_quant<<<(MR2 * C + 255) / 256, 256, 0, stream>>>(VQ, VQ, scal + 6, MR2 * C);
  k_vt<<<dim3(2, 160), 256, 0, stream>>>(VQ, VT, H, 77, 128);
  k_attn1<<<dim3(16, 160), 256, 0, stream>>>(QQ, KQ, RS, scal + 7, H, Nseq, 77, 0.125f);
  k_attn2<<<dim3(16, 160), 256, 0, stream>>>(QQ, KQ, VT, RS, scal + 7, AO,
                                             H, Nseq, 77, 128, 0.125f);
  k_gemm<<<dim3(10, 64), 256, 0, stream>>>(AO, C, Wo2T, C, out, nullptr, C,
                                           bo2, out, nullptr, NR, C, C);

  // ================= stage 3: GEGLU FF (fused, no H1 materialization) =================
  k_ln<<<NR, 256, 0, stream>>>(out, ln3g, ln3b, LN);
  k_ff1<<<dim3(80, 64), 256, 0, stream>>>(LN, WF1T, bff1, GG);
  k_gemm<<<dim3(10, 64), 256, 0, stream>>>(GG, 5120, WF2T, 5120, out, nullptr, C,
                                           bff2, out, nullptr, NR, C, 5120);
}

// Round 5
// 1928.164 us; speedup vs baseline: 5.7862x; 3.7416x over previous
//
#include <hip/hip_runtime.h>

typedef __attribute__((ext_vector_type(8))) short bf16x8;
typedef __attribute__((ext_vector_type(4))) float f32x4;

#define DEV __device__ __forceinline__
#define MF(A, B, CACC) CACC = __builtin_amdgcn_mfma_f32_16x16x32_bf16(A, B, CACC, 0, 0, 0)

DEV ushort f2b(float f) {
  unsigned u = __float_as_uint(f);
  u += 0x7fffu + ((u >> 16) & 1u);   // RNE to bf16
  return (ushort)(u >> 16);
}
DEV float b2f(ushort u) { return __uint_as_float(((unsigned)u) << 16); }

// async global->LDS, 16B per lane; lds base must be wave-uniform (HW adds lane*16)
DEV void gl_lds16(ushort* lds_base, const ushort* gp) {
  __builtin_amdgcn_global_load_lds(
      (__attribute__((address_space(1))) const void*)gp,
      (__attribute__((address_space(3))) void*)lds_base, 16, 0, 0);
}

// ---------------- zero scalar slots ----------------
__global__ void k_zero(unsigned* p, int n) {
  int i = blockIdx.x * blockDim.x + threadIdx.x;
  if (i < n) p[i] = 0u;
}

// ------------- weight transpose fp32 W[K][N] -> bf16 WT[N][K] -------------
__global__ __launch_bounds__(256) void k_wt(const float* __restrict__ W,
                                            ushort* __restrict__ WT, int K, int N) {
  __shared__ float T[32][33];
  int k0 = blockIdx.y * 32, n0 = blockIdx.x * 32;
  int tx = threadIdx.x & 31, ty = threadIdx.x >> 5;
  #pragma unroll
  for (int r = ty; r < 32; r += 8) {
    int k = k0 + r, n = n0 + tx;
    T[r][tx] = (k < K && n < N) ? W[(size_t)k * N + n] : 0.f;
  }
  __syncthreads();
  #pragma unroll
  for (int r = ty; r < 32; r += 8) {
    int n = n0 + r, k = k0 + tx;
    if (n < N && k < K) WT[(size_t)n * K + k] = f2b(T[tx][r]);
  }
}

// ---------------- f32 -> bf16 elementwise ----------------
__global__ void k_cvt(const float* __restrict__ in, ushort* __restrict__ out, int n) {
  int i = blockIdx.x * 256 + threadIdx.x;
  if (i < n) out[i] = f2b(in[i]);
}

// ---------------- layernorm (C==1280), out bf16 ----------------
__global__ __launch_bounds__(256) void k_ln(const float* __restrict__ x,
    const float* __restrict__ g, const float* __restrict__ b,
    ushort* __restrict__ out) {
  const int C = 1280;
  int row = blockIdx.x, tid = threadIdx.x;
  const float* xr = x + (size_t)row * C;
  float v0 = xr[tid], v1 = xr[tid + 256], v2 = xr[tid + 512],
        v3 = xr[tid + 768], v4 = xr[tid + 1024];
  float s = v0 + v1 + v2 + v3 + v4;
  float ss = v0 * v0 + v1 * v1 + v2 * v2 + v3 * v3 + v4 * v4;
  #pragma unroll
  for (int off = 32; off; off >>= 1) {
    s += __shfl_down(s, off);
    ss += __shfl_down(ss, off);
  }
  __shared__ float red[8];
  __shared__ float mu_s, rstd_s;
  int wave = tid >> 6, lane = tid & 63;
  if (lane == 0) { red[wave] = s; red[4 + wave] = ss; }
  __syncthreads();
  if (tid == 0) {
    float S = red[0] + red[1] + red[2] + red[3];
    float SS = red[4] + red[5] + red[6] + red[7];
    float mu = S / C;
    float var = SS / C - mu * mu;
    mu_s = mu;
    rstd_s = rsqrtf(var + 1e-5f);
  }
  __syncthreads();
  float mu = mu_s, rstd = rstd_s;
  size_t o = (size_t)row * C + tid;
  out[o]        = f2b((v0 - mu) * rstd * g[tid]        + b[tid]);
  out[o + 256]  = f2b((v1 - mu) * rstd * g[tid + 256]  + b[tid + 256]);
  out[o + 512]  = f2b((v2 - mu) * rstd * g[tid + 512]  + b[tid + 512]);
  out[o + 768]  = f2b((v3 - mu) * rstd * g[tid + 768]  + b[tid + 768]);
  out[o + 1024] = f2b((v4 - mu) * rstd * g[tid + 1024] + b[tid + 1024]);
}

// ---- GEMM epilogue helpers (by-value f32x4, constant swizzles: SROA-proof) ----
DEV void st1(float v, int r_, int c_, int ldc, const float* resid,
             float* Cf, ushort* Cb) {
  size_t o = (size_t)r_ * ldc + c_;
  if (resid) v += resid[o];
  if (Cf) Cf[o] = v;
  if (Cb) Cb[o] = f2b(v);
}
DEV float epi4(f32x4 v, int rbase, int c_, int M, int N, int ldc,
               const float* bias, const float* resid, float* Cf, ushort* Cb) {
  float v0 = v.x, v1 = v.y, v2 = v.z, v3 = v.w;
  float am = fmaxf(fmaxf(fabsf(v0), fabsf(v1)), fmaxf(fabsf(v2), fabsf(v3)));
  if (c_ < N) {
    float bb = bias ? bias[c_] : 0.f;
    v0 += bb; v1 += bb; v2 += bb; v3 += bb;
    if (rbase + 0 < M) st1(v0, rbase + 0, c_, ldc, resid, Cf, Cb);
    if (rbase + 1 < M) st1(v1, rbase + 1, c_, ldc, resid, Cf, Cb);
    if (rbase + 2 < M) st1(v2, rbase + 2, c_, ldc, resid, Cf, Cb);
    if (rbase + 3 < M) st1(v3, rbase + 3, c_, ldc, resid, Cf, Cb);
  }
  return am;
}

// ---------------- bf16 NT GEMM: C[M,N] = A[M,K] @ BT[N,K]^T ----------------
// 128x128 tile, 4 waves (2x2 of 64x64), 16x16x32 MFMA, BK=32,
// global_load_lds width=16 staging, NAMED scalar accumulators (no reg arrays).
__global__ __launch_bounds__(256) void k_gemm(
    const ushort* __restrict__ A, int lda,
    const ushort* __restrict__ BT, int ldb,
    float* __restrict__ Cf, ushort* __restrict__ Cb, int ldc,
    const float* __restrict__ bias, const float* __restrict__ resid,
    unsigned* am_slot, int M, int N, int K) {
  __shared__ __align__(16) ushort SAB[8192];  // A[128][32] @0, B[128][32] @4096
  int tid = threadIdx.x;
  int wave = tid >> 6, lane = tid & 63;
  int q = lane >> 4, mi = lane & 15;
  int wr = (wave >> 1) * 64, wc = (wave & 1) * 64;
  int bm0 = blockIdx.y * 128, bn0 = blockIdx.x * 128;
  f32x4 c00 = {}, c01 = {}, c02 = {}, c03 = {};
  f32x4 c10 = {}, c11 = {}, c12 = {}, c13 = {};
  f32x4 c20 = {}, c21 = {}, c22 = {}, c23 = {};
  f32x4 c30 = {}, c31 = {}, c32 = {}, c33 = {};
  for (int k0 = 0; k0 < K; k0 += 32) {
    __syncthreads();
    #pragma unroll
    for (int t = 0; t < 4; t++) {
      int c = wave * 256 + t * 64 + lane;
      const ushort* gp;
      if (c < 512) {
        int r = c >> 2, kc = (c & 3) << 3;
        int gr = bm0 + r; if (gr >= M) gr = M - 1;
        gp = A + (size_t)gr * lda + k0 + kc;
      } else {
        int c2 = c - 512;
        int r = c2 >> 2, kc = (c2 & 3) << 3;
        int gn = bn0 + r; if (gn >= N) gn = N - 1;
        gp = BT + (size_t)gn * ldb + k0 + kc;
      }
      gl_lds16(&SAB[(wave * 256 + t * 64) * 8], gp);
    }
    __syncthreads();
    const ushort* Ab = &SAB[(wr + mi) * 32 + q * 8];
    const ushort* Bb = &SAB[4096 + (wc + mi) * 32 + q * 8];
    bf16x8 a0 = *(const bf16x8*)(Ab);
    bf16x8 a1 = *(const bf16x8*)(Ab + 512);
    bf16x8 a2 = *(const bf16x8*)(Ab + 1024);
    bf16x8 a3 = *(const bf16x8*)(Ab + 1536);
    bf16x8 b0 = *(const bf16x8*)(Bb);
    bf16x8 b1 = *(const bf16x8*)(Bb + 512);
    bf16x8 b2 = *(const bf16x8*)(Bb + 1024);
    bf16x8 b3 = *(const bf16x8*)(Bb + 1536);
    MF(a0, b0, c00); MF(a0, b1, c01); MF(a0, b2, c02); MF(a0, b3, c03);
    MF(a1, b0, c10); MF(a1, b1, c11); MF(a1, b2, c12); MF(a1, b3, c13);
    MF(a2, b0, c20); MF(a2, b1, c21); MF(a2, b2, c22); MF(a2, b3, c23);
    MF(a3, b0, c30); MF(a3, b1, c31); MF(a3, b2, c32); MF(a3, b3, c33);
  }
  int rb = bm0 + wr + q * 4, cb = bn0 + wc + mi;
  float am = 0.f;
  am = fmaxf(am, epi4(c00, rb +  0, cb +  0, M, N, ldc, bias, resid, Cf, Cb));
  am = fmaxf(am, epi4(c01, rb +  0, cb + 16, M, N, ldc, bias, resid, Cf, Cb));
  am = fmaxf(am, epi4(c02, rb +  0, cb + 32, M, N, ldc, bias, resid, Cf, Cb));
  am = fmaxf(am, epi4(c03, rb +  0, cb + 48, M, N, ldc, bias, resid, Cf, Cb));
  am = fmaxf(am, epi4(c10, rb + 16, cb +  0, M, N, ldc, bias, resid, Cf, Cb));
  am = fmaxf(am, epi4(c11, rb + 16, cb + 16, M, N, ldc, bias, resid, Cf, Cb));
  am = fmaxf(am, epi4(c12, rb + 16, cb + 32, M, N, ldc, bias, resid, Cf, Cb));
  am = fmaxf(am, epi4(c13, rb + 16, cb + 48, M, N, ldc, bias, resid, Cf, Cb));
  am = fmaxf(am, epi4(c20, rb + 32, cb +  0, M, N, ldc, bias, resid, Cf, Cb));
  am = fmaxf(am, epi4(c21, rb + 32, cb + 16, M, N, ldc, bias, resid, Cf, Cb));
  am = fmaxf(am, epi4(c22, rb + 32, cb + 32, M, N, ldc, bias, resid, Cf, Cb));
  am = fmaxf(am, epi4(c23, rb + 32, cb + 48, M, N, ldc, bias, resid, Cf, Cb));
  am = fmaxf(am, epi4(c30, rb + 48, cb +  0, M, N, ldc, bias, resid, Cf, Cb));
  am = fmaxf(am, epi4(c31, rb + 48, cb + 16, M, N, ldc, bias, resid, Cf, Cb));
  am = fmaxf(am, epi4(c32, rb + 48, cb + 32, M, N, ldc, bias, resid, Cf, Cb));
  am = fmaxf(am, epi4(c33, rb + 48, cb + 48, M, N, ldc, bias, resid, Cf, Cb));
  if (am_slot) {
    #pragma unroll
    for (int off = 32; off; off >>= 1) am = fmaxf(am, __shfl_down(am, off));
    if (lane == 0) atomicMax(am_slot, __float_as_uint(am));
  }
}

// ---------------- symmetric fake-quant, in-place on bf16 ----------------
__global__ void k_quant(const ushort* __restrict__ in, ushort* __restrict__ out,
                        const unsigned* __restrict__ slot, int n) {
  int i = blockIdx.x * 256 + threadIdx.x;
  if (i >= n) return;
  float delta = fmaxf(__uint_as_float(*slot), 1e-8f) * (1.f / 127.f);
  float x = b2f(in[i]);
  float y = fminf(fmaxf(rintf(x / delta), -128.f), 127.f) * delta;
  out[i] = f2b(y);
}

// ------- V transpose per head: vq[b*Mr+m][h*64+d] -> vT[bh][d][m] (zero-pad) -------
__global__ __launch_bounds__(256) void k_vt(const ushort* __restrict__ vq,
    ushort* __restrict__ vT, int H, int Mr, int Mpad) {
  const int C = 1280;
  __shared__ __align__(16) ushort T[64][72];
  int bh = blockIdx.y, b = bh / H, h = bh % H;
  int m0 = blockIdx.x * 64;
  int tid = threadIdx.x;
  #pragma unroll
  for (int c = tid; c < 512; c += 256) {
    int mm = c >> 3, dc = (c & 7) << 3;
    int m = m0 + mm;
    int4 val = make_int4(0, 0, 0, 0);
    if (m < Mr) val = *(const int4*)(vq + ((size_t)b * Mr + m) * C + h * 64 + dc);
    *(int4*)&T[mm][dc] = val;
  }
  __syncthreads();
  #pragma unroll
  for (int c = tid; c < 512; c += 256) {
    int dd = c >> 3, mc = (c & 7) << 3;
    unsigned w0 = (unsigned)T[mc + 0][dd] | ((unsigned)T[mc + 1][dd] << 16);
    unsigned w1 = (unsigned)T[mc + 2][dd] | ((unsigned)T[mc + 3][dd] << 16);
    unsigned w2 = (unsigned)T[mc + 4][dd] | ((unsigned)T[mc + 5][dd] << 16);
    unsigned w3 = (unsigned)T[mc + 6][dd] | ((unsigned)T[mc + 7][dd] << 16);
    int4 val = make_int4((int)w0, (int)w1, (int)w2, (int)w3);
    *(int4*)(vT + ((size_t)bh * 64 + dd) * Mpad + m0 + mc) = val;
  }
}

// ------- attention phase 1: per-row smax & Z, global max(1/Z) -> pmax -------
__global__ __launch_bounds__(256) void k_attn1(
    const ushort* __restrict__ qq, const ushort* __restrict__ kq,
    float2* __restrict__ rs, unsigned* __restrict__ pmax,
    int H, int N, int Mr, float scale) {
  const int C = 1280;
  __shared__ __align__(16) ushort Qs[64][72];
  __shared__ __align__(16) ushort Ks[64][72];
  __shared__ float Ss[64][68];
  __shared__ float mq4[64][4], zq4[64][4];
  int tid = threadIdx.x;
  int wave = tid >> 6, lane = tid & 63;
  int q = lane >> 4, mi = lane & 15;
  int bh = blockIdx.y, b = bh / H, h = bh % H;
  int r0 = blockIdx.x * 64;
  #pragma unroll
  for (int c = tid; c < 512; c += 256) {
    int r = c >> 3, dc = (c & 7) << 3;
    *(int4*)&Qs[r][dc] = *(const int4*)(qq + ((size_t)b * N + r0 + r) * C + h * 64 + dc);
  }
  float m_run = -1e30f, z_run = 0.f;
  int row = tid >> 2, qt = tid & 3;
  int nt = (Mr + 63) >> 6;
  for (int mt = 0; mt < nt; mt++) {
    __syncthreads();
    #pragma unroll
    for (int c = tid; c < 512; c += 256) {
      int mm = c >> 3, dc = (c & 7) << 3;
      int m = mt * 64 + mm;
      int4 val = make_int4(0, 0, 0, 0);
      if (m < Mr) val = *(const int4*)(kq + ((size_t)b * Mr + m) * C + h * 64 + dc);
      *(int4*)&Ks[mm][dc] = val;
    }
    __syncthreads();
    f32x4 s0 = {}, s1 = {}, s2 = {}, s3 = {};
    #pragma unroll
    for (int kc = 0; kc < 2; kc++) {
      bf16x8 aq = *(const bf16x8*)&Qs[wave * 16 + mi][kc * 32 + q * 8];
      bf16x8 k0v = *(const bf16x8*)&Ks[mi][kc * 32 + q * 8];
      bf16x8 k1v = *(const bf16x8*)&Ks[16 + mi][kc * 32 + q * 8];
      bf16x8 k2v = *(const bf16x8*)&Ks[32 + mi][kc * 32 + q * 8];
      bf16x8 k3v = *(const bf16x8*)&Ks[48 + mi][kc * 32 + q * 8];
      MF(aq, k0v, s0); MF(aq, k1v, s1); MF(aq, k2v, s2); MF(aq, k3v, s3);
    }
    int rr = wave * 16 + q * 4;
    Ss[rr + 0][mi]      = s0.x * scale; Ss[rr + 1][mi]      = s0.y * scale;
    Ss[rr + 2][mi]      = s0.z * scale; Ss[rr + 3][mi]      = s0.w * scale;
    Ss[rr + 0][16 + mi] = s1.x * scale; Ss[rr + 1][16 + mi] = s1.y * scale;
    Ss[rr + 2][16 + mi] = s1.z * scale; Ss[rr + 3][16 + mi] = s1.w * scale;
    Ss[rr + 0][32 + mi] = s2.x * scale; Ss[rr + 1][32 + mi] = s2.y * scale;
    Ss[rr + 2][32 + mi] = s2.z * scale; Ss[rr + 3][32 + mi] = s2.w * scale;
    Ss[rr + 0][48 + mi] = s3.x * scale; Ss[rr + 1][48 + mi] = s3.y * scale;
    Ss[rr + 2][48 + mi] = s3.z * scale; Ss[rr + 3][48 + mi] = s3.w * scale;
    __syncthreads();
    #pragma unroll
    for (int cc = 0; cc < 16; cc++) {
      int col = qt * 16 + cc;
      int mg = mt * 64 + col;
      if (mg < Mr) {
        float sv = Ss[row][col];
        if (sv <= m_run) {
          z_run += __expf(sv - m_run);
        } else {
          z_run = z_run * __expf(m_run - sv) + 1.f;
          m_run = sv;
        }
      }
    }
  }
  __syncthreads();
  mq4[row][qt] = m_run; zq4[row][qt] = z_run;
  __syncthreads();
  if (tid < 64) {
    float M0 = mq4[tid][0], M1 = mq4[tid][1], M2 = mq4[tid][2], M3 = mq4[tid][3];
    float M_ = fmaxf(fmaxf(M0, M1), fmaxf(M2, M3));
    float Z = zq4[tid][0] * __expf(M0 - M_) + zq4[tid][1] * __expf(M1 - M_) +
              zq4[tid][2] * __expf(M2 - M_) + zq4[tid][3] * __expf(M3 - M_);
    float2 st; st.x = M_; st.y = Z;
    rs[(size_t)bh * N + r0 + tid] = st;
    float pm = 1.f / Z;
    #pragma unroll
    for (int off = 32; off; off >>= 1) pm = fmaxf(pm, __shfl_down(pm, off));
    if (tid == 0) atomicMax(pmax, __float_as_uint(pm));
  }
}

// ------- attention phase 2: recompute S, quantize probs, P@V -> ao (bf16) -------
__global__ __launch_bounds__(256) void k_attn2(
    const ushort* __restrict__ qq, const ushort* __restrict__ kq,
    const ushort* __restrict__ vT, const float2* __restrict__ rs,
    const unsigned* __restrict__ pmax, ushort* __restrict__ ao,
    int H, int N, int Mr, int Mpad, float scale) {
  const int C = 1280;
  __shared__ __align__(16) ushort Qs[64][72];
  __shared__ __align__(16) ushort Ks[64][72];
  __shared__ __align__(16) ushort Vs[64][72];
  __shared__ __align__(16) ushort Ps[64][72];
  __shared__ float Ss[64][68];
  int tid = threadIdx.x;
  int wave = tid >> 6, lane = tid & 63;
  int q = lane >> 4, mi = lane & 15;
  int bh = blockIdx.y, b = bh / H, h = bh % H;
  int r0 = blockIdx.x * 64;
  #pragma unroll
  for (int c = tid; c < 512; c += 256) {
    int r = c >> 3, dc = (c & 7) << 3;
    *(int4*)&Qs[r][dc] = *(const int4*)(qq + ((size_t)b * N + r0 + r) * C + h * 64 + dc);
  }
  int row = tid >> 2, qt = tid & 3;
  float2 st = rs[(size_t)bh * N + r0 + row];
  float delta = fmaxf(__uint_as_float(*pmax), 1e-8f) * (1.f / 255.f);
  float invd = 1.f / delta;
  f32x4 o0 = {}, o1 = {}, o2 = {}, o3 = {};
  int nt = (Mr + 63) >> 6;
  for (int mt = 0; mt < nt; mt++) {
    __syncthreads();
    #pragma unroll
    for (int c = tid; c < 512; c += 256) {
      int mm = c >> 3, dc = (c & 7) << 3;
      int m = mt * 64 + mm;
      int4 val = make_int4(0, 0, 0, 0);
      if (m < Mr) val = *(const int4*)(kq + ((size_t)b * Mr + m) * C + h * 64 + dc);
      *(int4*)&Ks[mm][dc] = val;
      *(int4*)&Vs[mm][dc] = *(const int4*)(vT + ((size_t)bh * 64 + mm) * Mpad + mt * 64 + dc);
    }
    __syncthreads();
    f32x4 s0 = {}, s1 = {}, s2 = {}, s3 = {};
    #pragma unroll
    for (int kc = 0; kc < 2; kc++) {
      bf16x8 aq = *(const bf16x8*)&Qs[wave * 16 + mi][kc * 32 + q * 8];
      bf16x8 k0v = *(const bf16x8*)&Ks[mi][kc * 32 + q * 8];
      bf16x8 k1v = *(const bf16x8*)&Ks[16 + mi][kc * 32 + q * 8];
      bf16x8 k2v = *(const bf16x8*)&Ks[32 + mi][kc * 32 + q * 8];
      bf16x8 k3v = *(const bf16x8*)&Ks[48 + mi][kc * 32 + q * 8];
      MF(aq, k0v, s0); MF(aq, k1v, s1); MF(aq, k2v, s2); MF(aq, k3v, s3);
    }
    int rr = wave * 16 + q * 4;
    Ss[rr + 0][mi]      = s0.x * scale; Ss[rr + 1][mi]      = s0.y * scale;
    Ss[rr + 2][mi]      = s0.z * scale; Ss[rr + 3][mi]      = s0.w * scale;
    Ss[rr + 0][16 + mi] = s1.x * scale; Ss[rr + 1][16 + mi] = s1.y * scale;
    Ss[rr + 2][16 + mi] = s1.z * scale; Ss[rr + 3][16 + mi] = s1.w * scale;
    Ss[rr + 0][32 + mi] = s2.x * scale; Ss[rr + 1][32 + mi] = s2.y * scale;
    Ss[rr + 2][32 + mi] = s2.z * scale; Ss[rr + 3][32 + mi] = s2.w * scale;
    Ss[rr + 0][48 + mi] = s3.x * scale; Ss[rr + 1][48 + mi] = s3.y * scale;
    Ss[rr + 2][48 + mi] = s3.z * scale; Ss[rr + 3][48 + mi] = s3.w * scale;
    __syncthreads();
    #pragma unroll
    for (int cc = 0; cc < 16; cc++) {
      int col = qt * 16 + cc;
      int mg = mt * 64 + col;
      float p = 0.f;
      if (mg < Mr) {
        float sv = Ss[row][col];
        p = __expf(sv - st.x) / st.y;
        p = fminf(rintf(p * invd), 255.f) * delta;
      }
      Ps[row][col] = f2b(p);
    }
    __syncthreads();
    #pragma unroll
    for (int kc = 0; kc < 2; kc++) {
      bf16x8 ap = *(const bf16x8*)&Ps[wave * 16 + mi][kc * 32 + q * 8];
      bf16x8 v0 = *(const bf16x8*)&Vs[mi][kc * 32 + q * 8];
      bf16x8 v1 = *(const bf16x8*)&Vs[16 + mi][kc * 32 + q * 8];
      bf16x8 v2 = *(const bf16x8*)&Vs[32 + mi][kc * 32 + q * 8];
      bf16x8 v3 = *(const bf16x8*)&Vs[48 + mi][kc * 32 + q * 8];
      MF(ap, v0, o0); MF(ap, v1, o1); MF(ap, v2, o2); MF(ap, v3, o3);
    }
  }
  int rr = r0 + wave * 16 + q * 4;
  size_t base = ((size_t)b * N + rr) * C + h * 64 + mi;
  ao[base]             = f2b(o0.x); ao[base + C]         = f2b(o0.y);
  ao[base + 2 * C]     = f2b(o0.z); ao[base + 3 * C]     = f2b(o0.w);
  ao[base + 16]        = f2b(o1.x); ao[base + C + 16]    = f2b(o1.y);
  ao[base + 2 * C + 16] = f2b(o1.z); ao[base + 3 * C + 16] = f2b(o1.w);
  ao[base + 32]        = f2b(o2.x); ao[base + C + 32]    = f2b(o2.y);
  ao[base + 2 * C + 32] = f2b(o2.z); ao[base + 3 * C + 32] = f2b(o2.w);
  ao[base + 48]        = f2b(o3.x); ao[base + C + 48]    = f2b(o3.y);
  ao[base + 2 * C + 48] = f2b(o3.z); ao[base + 3 * C + 48] = f2b(o3.w);
}

// ---- GEGLU scalar ----
DEV ushort gg1(float a, float g) {
  float y = 0.7978845608028654f * (g + 0.044715f * g * g * g);
  return f2b(a * 0.5f * g * (1.f + tanhf(y)));
}
DEV void geglu4(f32x4 va, f32x4 vg, int rbase, int c_, float ba, float bg,
                ushort* GG) {
  GG[(size_t)(rbase + 0) * 5120 + c_] = gg1(va.x + ba, vg.x + bg);
  GG[(size_t)(rbase + 1) * 5120 + c_] = gg1(va.y + ba, vg.y + bg);
  GG[(size_t)(rbase + 2) * 5120 + c_] = gg1(va.z + ba, vg.z + bg);
  GG[(size_t)(rbase + 3) * 5120 + c_] = gg1(va.w + ba, vg.w + bg);
}

// ------- fused FF1 + GEGLU: GG[r][c] = (A@W)[r][c]+b * gelu((A@W)[r][c+5120]+b) -------
// 128(M)x64(N) tile for BOTH halves, named accumulators.
__global__ __launch_bounds__(256) void k_ff1(
    const ushort* __restrict__ A,          // LN [8192][1280]
    const ushort* __restrict__ BT,         // WF1T [10240][1280]
    const float* __restrict__ bias,        // bff1 [10240]
    ushort* __restrict__ GG) {             // [8192][5120]
  const int K = 1280;
  __shared__ __align__(16) ushort SAB[8192]; // A[128][32]@0, Ba[64][32]@4096, Bg[64][32]@6144
  int tid = threadIdx.x;
  int wave = tid >> 6, lane = tid & 63;
  int q = lane >> 4, mi = lane & 15;
  int wr = (wave >> 1) * 64, wc = (wave & 1) * 32;
  int bm0 = blockIdx.y * 128, bn0 = blockIdx.x * 64;
  f32x4 a00 = {}, a01 = {}, a10 = {}, a11 = {}, a20 = {}, a21 = {}, a30 = {}, a31 = {};
  f32x4 g00 = {}, g01 = {}, g10 = {}, g11 = {}, g20 = {}, g21 = {}, g30 = {}, g31 = {};
  for (int k0 = 0; k0 < K; k0 += 32) {
    __syncthreads();
    #pragma unroll
    for (int t = 0; t < 4; t++) {
      int c = wave * 256 + t * 64 + lane;
      const ushort* gp;
      if (c < 512) {
        int r = c >> 2, kc = (c & 3) << 3;
        gp = A + (size_t)(bm0 + r) * K + k0 + kc;
      } else if (c < 768) {
        int c2 = c - 512; int r = c2 >> 2, kc = (c2 & 3) << 3;
        gp = BT + (size_t)(bn0 + r) * K + k0 + kc;
      } else {
        int c2 = c - 768; int r = c2 >> 2, kc = (c2 & 3) << 3;
        gp = BT + (size_t)(5120 + bn0 + r) * K + k0 + kc;
      }
      gl_lds16(&SAB[(wave * 256 + t * 64) * 8], gp);
    }
    __syncthreads();
    const ushort* Ab = &SAB[(wr + mi) * 32 + q * 8];
    bf16x8 f0 = *(const bf16x8*)(Ab);
    bf16x8 f1 = *(const bf16x8*)(Ab + 512);
    bf16x8 f2 = *(const bf16x8*)(Ab + 1024);
    bf16x8 f3 = *(const bf16x8*)(Ab + 1536);
    const ushort* Bab = &SAB[4096 + (wc + mi) * 32 + q * 8];
    bf16x8 ba0 = *(const bf16x8*)(Bab);
    bf16x8 ba1 = *(const bf16x8*)(Bab + 512);
    const ushort* Bgb = &SAB[6144 + (wc + mi) * 32 + q * 8];
    bf16x8 bg0 = *(const bf16x8*)(Bgb);
    bf16x8 bg1 = *(const bf16x8*)(Bgb + 512);
    MF(f0, ba0, a00); MF(f0, ba1, a01); MF(f0, bg0, g00); MF(f0, bg1, g01);
    MF(f1, ba0, a10); MF(f1, ba1, a11); MF(f1, bg0, g10); MF(f1, bg1, g11);
    MF(f2, ba0, a20); MF(f2, ba1, a21); MF(f2, bg0, g20); MF(f2, bg1, g21);
    MF(f3, ba0, a30); MF(f3, ba1, a31); MF(f3, bg0, g30); MF(f3, bg1, g31);
  }
  int rb = bm0 + wr + q * 4, cb = bn0 + wc + mi;
  float ba_ = bias[cb], bg_ = bias[5120 + cb];
  float ba16 = bias[cb + 16], bg16 = bias[5120 + cb + 16];
  geglu4(a00, g00, rb +  0, cb,      ba_,  bg_,  GG);
  geglu4(a01, g01, rb +  0, cb + 16, ba16, bg16, GG);
  geglu4(a10, g10, rb + 16, cb,      ba_,  bg_,  GG);
  geglu4(a11, g11, rb + 16, cb + 16, ba16, bg16, GG);
  geglu4(a20, g20, rb + 32, cb,      ba_,  bg_,  GG);
  geglu4(a21, g21, rb + 32, cb + 16, ba16, bg16, GG);
  geglu4(a30, g30, rb + 48, cb,      ba_,  bg_,  GG);
  geglu4(a31, g31, rb + 48, cb + 16, ba16, bg16, GG);
}

extern "C" void kernel_launch(void* const* d_in, const int* in_sizes, int n_in,
                              void* d_out, int out_size, void* d_ws, size_t ws_size,
                              hipStream_t stream) {
  const float* x_in = (const float*)d_in[0];
  const float* ctx  = (const float*)d_in[1];
  const float* ln1g = (const float*)d_in[2];
  const float* ln1b = (const float*)d_in[3];
  const float* ln2g = (const float*)d_in[4];
  const float* ln2b = (const float*)d_in[5];
  const float* ln3g = (const float*)d_in[6];
  const float* ln3b = (const float*)d_in[7];
  const float* Wq1  = (const float*)d_in[8];
  const float* Wk1  = (const float*)d_in[9];
  const float* Wv1  = (const float*)d_in[10];
  const float* Wo1  = (const float*)d_in[11];
  const float* bo1  = (const float*)d_in[12];
  const float* Wq2  = (const float*)d_in[13];
  const float* Wk2  = (const float*)d_in[14];
  const float* Wv2  = (const float*)d_in[15];
  const float* Wo2  = (const float*)d_in[16];
  const float* bo2  = (const float*)d_in[17];
  const float* Wff1 = (const float*)d_in[18];
  const float* bff1 = (const float*)d_in[19];
  const float* Wff2 = (const float*)d_in[20];
  const float* bff2 = (const float*)d_in[21];
  float* out = (float*)d_out;   // also doubles as the fp32 residual stream "xcur"

  const int NR = 8192;   // B*N
  const int C = 1280, H = 20, Nseq = 1024, CC = 768;
  const int MR2 = 616;   // B*M (cross rows)

  char* ws = (char*)d_ws;
  size_t off = 0;
  auto alloc = [&](size_t bytes) -> void* {
    void* p = ws + off;
    off += (bytes + 255) & ~(size_t)255;
    return p;
  };
  unsigned* scal = (unsigned*)alloc(64);
  ushort* Wq1T  = (ushort*)alloc((size_t)C * C * 2);
  ushort* Wk1T  = (ushort*)alloc((size_t)C * C * 2);
  ushort* Wv1T  = (ushort*)alloc((size_t)C * C * 2);
  ushort* Wo1T  = (ushort*)alloc((size_t)C * C * 2);
  ushort* Wq2T  = (ushort*)alloc((size_t)C * C * 2);
  ushort* Wk2T  = (ushort*)alloc((size_t)C * CC * 2);
  ushort* Wv2T  = (ushort*)alloc((size_t)C * CC * 2);
  ushort* Wo2T  = (ushort*)alloc((size_t)C * C * 2);
  ushort* WF1T  = (ushort*)alloc((size_t)10240 * C * 2);
  ushort* WF2T  = (ushort*)alloc((size_t)C * 5120 * 2);
  ushort* LN    = (ushort*)alloc((size_t)NR * C * 2);
  size_t regionR = off;  // attention region; stage-3 GG overlays it
  ushort* QQ    = (ushort*)alloc((size_t)NR * C * 2);
  ushort* KQ    = (ushort*)alloc((size_t)NR * C * 2);
  ushort* VQ    = (ushort*)alloc((size_t)NR * C * 2);  // also AO after k_vt
  ushort* VT    = (ushort*)alloc((size_t)160 * 64 * 1024 * 2);
  float2* RS    = (float2*)alloc((size_t)160 * 1024 * 8);
  ushort* CTXB  = (ushort*)alloc((size_t)MR2 * CC * 2);
  size_t need = off;
  ushort* AO = VQ;                       // alias: VQ dead once VT is built
  ushort* GG = (ushort*)(ws + regionR);  // 84 MB, overlays QQ..VT in stage 3
  if (ws_size < need) return;  // diagnostic: absmax==poison => ws too small

  // --- init & weight prep ---
  k_zero<<<1, 64, 0, stream>>>(scal, 8);
  k_wt<<<dim3(40, 40), 256, 0, stream>>>(Wq1, Wq1T, C, C);
  k_wt<<<dim3(40, 40), 256, 0, stream>>>(Wk1, Wk1T, C, C);
  k_wt<<<dim3(40, 40), 256, 0, stream>>>(Wv1, Wv1T, C, C);
  k_wt<<<dim3(40, 40), 256, 0, stream>>>(Wo1, Wo1T, C, C);
  k_wt<<<dim3(40, 40), 256, 0, stream>>>(Wq2, Wq2T, C, C);
  k_wt<<<dim3(40, 24), 256, 0, stream>>>(Wk2, Wk2T, CC, C);
  k_wt<<<dim3(40, 24), 256, 0, stream>>>(Wv2, Wv2T, CC, C);
  k_wt<<<dim3(40, 40), 256, 0, stream>>>(Wo2, Wo2T, C, C);
  k_wt<<<dim3(320, 40), 256, 0, stream>>>(Wff1, WF1T, C, 10240);
  k_wt<<<dim3(40, 160), 256, 0, stream>>>(Wff2, WF2T, 5120, C);

  // ================= stage 1: self-attention =================
  k_ln<<<NR, 256, 0, stream>>>(x_in, ln1g, ln1b, LN);
  k_gemm<<<dim3(10, 64), 256, 0, stream>>>(LN, C, Wq1T, C, nullptr, QQ, C,
                                           nullptr, nullptr, scal + 0, NR, C, C);
  k_quant<<<(NR * C + 255) / 256, 256, 0, stream>>>(QQ, QQ, scal + 0, NR * C);
  k_gemm<<<dim3(10, 64), 256, 0, stream>>>(LN, C, Wk1T, C, nullptr, KQ, C,
                                           nullptr, nullptr, scal + 1, NR, C, C);
  k_quant<<<(NR * C + 255) / 256, 256, 0, stream>>>(KQ, KQ, scal + 1, NR * C);
  k_gemm<<<dim3(10, 64), 256, 0, stream>>>(LN, C, Wv1T, C, nullptr, VQ, C,
                                           nullptr, nullptr, scal + 2, NR, C, C);
  k_quant<<<(NR * C + 255) / 256, 256, 0, stream>>>(VQ, VQ, scal + 2, NR * C);
  k_vt<<<dim3(16, 160), 256, 0, stream>>>(VQ, VT, H, 1024, 1024);
  k_attn1<<<dim3(16, 160), 256, 0, stream>>>(QQ, KQ, RS, scal + 3, H, Nseq, 1024, 0.125f);
  k_attn2<<<dim3(16, 160), 256, 0, stream>>>(QQ, KQ, VT, RS, scal + 3, AO,
                                             H, Nseq, 1024, 1024, 0.125f);
  k_gemm<<<dim3(10, 64), 256, 0, stream>>>(AO, C, Wo1T, C, out, nullptr, C,
                                           bo1, x_in, nullptr, NR, C, C);

  // ================= stage 2: cross-attention =================
  k_ln<<<NR, 256, 0, stream>>>(out, ln2g, ln2b, LN);
  k_gemm<<<dim3(10, 64), 256, 0, stream>>>(LN, C, Wq2T, C, nullptr, QQ, C,
                                           nullptr, nullptr, scal + 4, NR, C, C);
  k_quant<<<(NR * C + 255) / 256, 256, 0, stream>>>(QQ, QQ, scal + 4, NR * C);
  k_cvt<<<(MR2 * CC + 255) / 256, 256, 0, stream>>>(ctx, CTXB, MR2 * CC);
  k_gemm<<<dim3(10, 5), 256, 0, stream>>>(CTXB, CC, Wk2T, CC, nullptr, KQ, C,
                                          nullptr, nullptr, scal + 5, MR2, C, CC);
  k_quant<<<(MR2 * C + 255) / 256, 256, 0, stream>>>(KQ, KQ, scal + 5, MR2 * C);
  k_gemm<<<dim3(10, 5), 256, 0, stream>>>(CTXB, CC, Wv2T, CC, nullptr, VQ, C,
                                          nullptr, nullptr, scal + 6, MR2, C, CC);
  k_quant<<<(MR2 * C + 255) / 256, 256, 0, stream>>>(VQ, VQ, scal + 6, MR2 * C);
  k_vt<<<dim3(2, 160), 256, 0, stream>>>(VQ, VT, H, 77, 128);
  k_attn1<<<dim3(16, 160), 256, 0, stream>>>(QQ, KQ, RS, scal + 7, H, Nseq, 77, 0.125f);
  k_attn2<<<dim3(16, 160), 256, 0, stream>>>(QQ, KQ, VT, RS, scal + 7, AO,
                                             H, Nseq, 77, 128, 0.125f);
  k_gemm<<<dim3(10, 64), 256, 0, stream>>>(AO, C, Wo2T, C, out, nullptr, C,
                                           bo2, out, nullptr, NR, C, C);

  // ================= stage 3: GEGLU FF (fused, no H1 materialization) =================
  k_ln<<<NR, 256, 0, stream>>>(out, ln3g, ln3b, LN);
  k_ff1<<<dim3(80, 64), 256, 0, stream>>>(LN, WF1T, bff1, GG);
  k_gemm<<<dim3(10, 64), 256, 0, stream>>>(GG, 5120, WF2T, 5120, out, nullptr, C,
                                           bff2, out, nullptr, NR, C, 5120);
}